// Round 9
// baseline (182.573 us; speedup 1.0000x reference)
//
#include <hip/hip_runtime.h>

// DigitCaps dynamic routing, B=256 R=192 C=96 O=16 I=20. fp32 in/out.
// u_hat never materialized. 11 dispatches:
//   prep: W->WtT bf16 k-major; X->Xk + xT; bij=0
//   gemm1 (x3): 64x128 tile, grid (4,12,20)=960 blocks; pipelined K-loop
//     (raw prefetch after barrier + double LDS, 1 barrier/iter); cij scale
//     applied at B LDS-staging (it0: skipped, 1/192 folded into redsq);
//     partials stored transposed bf16 P^T[z][n][b]
//   redsq (x3): coalesced split-K reduce (+preScale) + squash -> vT / out
//   gemm2_agree (x2): LDS-staged pipelined; Z-tile in regs; agreement in
//     epilogue vs WtT, atomicAdd bij. K=256 split 2.
//   k_cij (x2): softmax(bij) -> cij[c][r] fp32 (c-major, coalesced for gemm1)

#define R_ 192
#define C_ 96
#define O_ 16
#define I_ 20
#define B_ 256
#define K1 3840   // R*I
#define N_ 1536   // C*O
#define ZSPLIT 20
#define STILE 393216  // N_*B_ elements per z-slice

typedef unsigned short u16;
typedef __attribute__((ext_vector_type(8))) short short8;
typedef __attribute__((ext_vector_type(4))) float floatx4;

__device__ inline float bf2f(u16 h) {
  union { unsigned int u; float f; } x; x.u = ((unsigned int)h) << 16; return x.f;
}
__device__ inline u16 f2bf(float f) {
  union { float f; unsigned int u; } x; x.f = f;
  unsigned int r = x.u + 0x7FFFu + ((x.u >> 16) & 1u);
  return (u16)(r >> 16);
}
__device__ inline unsigned int pack2(float a, float b) {
  return (unsigned int)f2bf(a) | ((unsigned int)f2bf(b) << 16);
}

// ---- fused prep: WtT gather (23040 blocks); X cast+transpose (240); bij=0 (72)
__global__ void k_prep(const float* __restrict__ W, const float* __restrict__ X,
                       u16* __restrict__ WtT, u16* __restrict__ Xk,
                       u16* __restrict__ xT, float* __restrict__ bij) {
  int bid = blockIdx.x;
  if (bid < 23040) {
    int t = bid * 256 + threadIdx.x;           // over N_*K1 = 5,898,240
    int n = t / K1, k = t - n * K1;
    int c = n >> 4, o = n & 15;
    int r = k / I_, i = k - r * I_;
    WtT[t] = f2bf(W[(((r * C_ + c) * O_ + o) * I_) + i]);
  } else if (bid < 23280) {
    __shared__ u16 tile[64][72];
    int idx = bid - 23040;
    int kb = (idx % 60) << 6, bb = (idx / 60) << 6;
    int brow = threadIdx.x >> 4;          // 0..15
    int kq = (threadIdx.x & 15) << 2;     // 0..60 step 4
    #pragma unroll
    for (int p = 0; p < 4; ++p) {
      int bl = p * 16 + brow;
      float4 v = *(const float4*)(X + (size_t)(bb + bl) * K1 + kb + kq);
      ushort4 h;
      h.x = f2bf(v.x); h.y = f2bf(v.y); h.z = f2bf(v.z); h.w = f2bf(v.w);
      *(ushort4*)(Xk + (size_t)(bb + bl) * K1 + kb + kq) = h;
      tile[kq + 0][bl] = h.x;
      tile[kq + 1][bl] = h.y;
      tile[kq + 2][bl] = h.z;
      tile[kq + 3][bl] = h.w;
    }
    __syncthreads();
    int kr = threadIdx.x >> 3;            // 0..31
    int bq = (threadIdx.x & 7) << 3;      // 0..56 step 8
    #pragma unroll
    for (int q = 0; q < 2; ++q) {
      int kl = q * 32 + kr;
      *(uint4*)(xT + (size_t)(kb + kl) * B_ + bb + bq) = *(const uint4*)&tile[kl][bq];
    }
  } else {
    int t = (bid - 23280) * 256 + threadIdx.x;  // bij: 18,432 floats
    bij[t] = 0.0f;
  }
}

// ---- softmax over r per capsule c -> cij[c*192+r] (c-major). 96 waves.
__global__ void k_cij(const float* __restrict__ bij, float* __restrict__ cij) {
  int c = blockIdx.x, l = threadIdx.x;
  float v0 = bij[l * C_ + c], v1 = bij[(l + 64) * C_ + c], v2 = bij[(l + 128) * C_ + c];
  float m = fmaxf(v0, fmaxf(v1, v2));
  #pragma unroll
  for (int off = 32; off > 0; off >>= 1) m = fmaxf(m, __shfl_xor(m, off));
  float e0 = expf(v0 - m), e1 = expf(v1 - m), e2 = expf(v2 - m);
  float s = e0 + e1 + e2;
  #pragma unroll
  for (int off = 32; off > 0; off >>= 1) s += __shfl_xor(s, off);
  float inv = 1.0f / s;
  cij[c * R_ + l] = e0 * inv;
  cij[c * R_ + l + 64] = e1 * inv;
  cij[c * R_ + l + 128] = e2 * inv;
}

// scale 8 k-contiguous bf16 (global k = kg..kg+7) by softmax row(s)
__device__ inline uint4 scale_b8(uint4 raw, int kg, const float* smrow) {
  int r0 = kg / I_;
  int bnd = (r0 + 1) * I_ - kg;                // elements j<bnd use r0
  float s0 = smrow[r0];
  float s1 = smrow[(r0 + 1 < R_) ? r0 + 1 : R_ - 1];
  union { uint4 q; u16 h[8]; } u; u.q = raw;
  #pragma unroll
  for (int j = 0; j < 8; ++j)
    u.h[j] = f2bf(bf2f(u.h[j]) * ((j < bnd) ? s0 : s1));
  return u.q;
}

// ---- GEMM1: P^T[z][n][b] bf16 = (Xk[256,3840] x (c*WtT)[1536,3840]^T),
// k-chunk z. 64x128 tile, BK=32, 4 waves of 64x32, grid (4,12,20)=960.
// Pipelined: raw prefetch after barrier, double LDS, 1 barrier/iter.
__global__ __launch_bounds__(256) void gemm1(
    const u16* __restrict__ A, const u16* __restrict__ Bt,
    const float* __restrict__ cij, u16* __restrict__ P, int doScale) {
  __shared__ u16 As[2][64 * 32];
  __shared__ u16 Bs[2][128 * 32];
  __shared__ float sm[8][192];
  int tid = threadIdx.x;
  if (doScale) {
    #pragma unroll
    for (int j = 0; j < 6; ++j) {
      int idx = tid + j * 256;               // 0..1535, coalesced
      int cl = idx / R_, r = idx - cl * R_;
      sm[cl][r] = cij[((blockIdx.y << 3) + cl) * R_ + r];
    }
  }

  int m0 = blockIdx.x << 6, n0 = blockIdx.y << 7;
  int k0 = blockIdx.z * 192;
  const u16* Ab = A + (size_t)m0 * K1 + k0;
  const u16* Bb = Bt + (size_t)n0 * K1 + k0;
  int srow = tid >> 2;              // 0..63
  int scol = (tid & 3) << 3;        // 0,8,16,24
  int w = tid >> 6, lane = tid & 63;
  int wn = w << 5;                  // wave covers 64m x 32n
  int quad = lane >> 4, lrow = lane & 15;
  int cl0 = srow >> 4;              // c_local of B row srow (0..3)
  floatx4 acc[4][2];
  #pragma unroll
  for (int a = 0; a < 4; ++a)
    #pragma unroll
    for (int b = 0; b < 2; ++b) acc[a][b] = (floatx4){0.f, 0.f, 0.f, 0.f};

  // initial raw load (kt = 0)
  uint4 a0 = *(const uint4*)(Ab + (size_t)srow * K1 + scol);
  uint4 b0 = *(const uint4*)(Bb + (size_t)srow * K1 + scol);
  uint4 b1 = *(const uint4*)(Bb + (size_t)(srow + 64) * K1 + scol);
  __syncthreads();                   // sm table ready

  int p = 0;
  for (int kt = 0; kt < 6; ++kt) {
    ((uint4*)As[p])[tid] = a0;
    if (doScale) {
      int kg = k0 + (kt << 5) + scol;
      ((uint4*)Bs[p])[tid] = scale_b8(b0, kg, &sm[cl0][0]);
      ((uint4*)Bs[p])[tid + 256] = scale_b8(b1, kg, &sm[cl0 + 4][0]);
    } else {
      ((uint4*)Bs[p])[tid] = b0;
      ((uint4*)Bs[p])[tid + 256] = b1;
    }
    __syncthreads();
    if (kt + 1 < 6) {                // prefetch escapes the barrier drain
      int kk = (kt + 1) << 5;
      a0 = *(const uint4*)(Ab + (size_t)srow * K1 + kk + scol);
      b0 = *(const uint4*)(Bb + (size_t)srow * K1 + kk + scol);
      b1 = *(const uint4*)(Bb + (size_t)(srow + 64) * K1 + kk + scol);
    }
    short8 af[4], bfr[2];
    #pragma unroll
    for (int ms = 0; ms < 4; ++ms)
      af[ms] = *(const short8*)&As[p][(ms * 16 + lrow) * 32 + (quad << 3)];
    #pragma unroll
    for (int ns = 0; ns < 2; ++ns)
      bfr[ns] = *(const short8*)&Bs[p][(wn + ns * 16 + lrow) * 32 + (quad << 3)];
    #pragma unroll
    for (int ms = 0; ms < 4; ++ms)
      #pragma unroll
      for (int ns = 0; ns < 2; ++ns)
        acc[ms][ns] = __builtin_amdgcn_mfma_f32_16x16x32_bf16(
            af[ms], bfr[ns], acc[ms][ns], 0, 0, 0);
    p ^= 1;
  }
  // transposed bf16 store: P[z][n*256 + b]; lane holds 4 consecutive b
  size_t zb = (size_t)blockIdx.z * (size_t)STILE;
  #pragma unroll
  for (int ms = 0; ms < 4; ++ms)
    #pragma unroll
    for (int ns = 0; ns < 2; ++ns) {
      int b = m0 + ms * 16 + (quad << 2);
      int n = n0 + wn + ns * 16 + lrow;
      uint2 pk;
      pk.x = pack2(acc[ms][ns][0], acc[ms][ns][1]);
      pk.y = pack2(acc[ms][ns][2], acc[ms][ns][3]);
      *(uint2*)&P[zb + (size_t)n * B_ + b] = pk;
    }
}

// ---- fused split-K reduce + squash, reading P^T[z][n][b] bf16.
// grid (96 c, 2 b-halves), block 256 = 4 o-groups x 64 lanes; 2 b per lane.
__global__ void k_redsq(const u16* __restrict__ P, float* __restrict__ out,
                        u16* __restrict__ vT, float preScale, int last) {
  __shared__ float nsq_l[4][128];
  int c = blockIdx.x, bh = blockIdx.y;
  int lane = threadIdx.x & 63, og = threadIdx.x >> 6;
  int bi = (lane << 1);                  // local b index (0..126 step 2)
  int b = (bh << 7) + bi;
  float acc[4][2];
  #pragma unroll
  for (int oo = 0; oo < 4; ++oo) { acc[oo][0] = 0.f; acc[oo][1] = 0.f; }
  for (int z = 0; z < ZSPLIT; ++z) {
    size_t base = (size_t)z * STILE + (size_t)((c << 4) + (og << 2)) * B_ + b;
    #pragma unroll
    for (int oo = 0; oo < 4; ++oo) {
      unsigned int u = *(const unsigned int*)&P[base + (size_t)oo * B_];
      acc[oo][0] += bf2f((u16)(u & 0xffff));
      acc[oo][1] += bf2f((u16)(u >> 16));
    }
  }
  #pragma unroll
  for (int oo = 0; oo < 4; ++oo) { acc[oo][0] *= preScale; acc[oo][1] *= preScale; }
  float q0 = 0.f, q1 = 0.f;
  #pragma unroll
  for (int oo = 0; oo < 4; ++oo) {
    q0 += acc[oo][0] * acc[oo][0];
    q1 += acc[oo][1] * acc[oo][1];
  }
  nsq_l[og][bi] = q0;
  nsq_l[og][bi + 1] = q1;
  __syncthreads();
  float n0 = nsq_l[0][bi] + nsq_l[1][bi] + nsq_l[2][bi] + nsq_l[3][bi];
  float n1 = nsq_l[0][bi + 1] + nsq_l[1][bi + 1] + nsq_l[2][bi + 1] + nsq_l[3][bi + 1];
  float f0 = n0 / ((1.0f + n0) * sqrtf(n0));
  float f1 = n1 / ((1.0f + n1) * sqrtf(n1));
  #pragma unroll
  for (int oo = 0; oo < 4; ++oo) { acc[oo][0] *= f0; acc[oo][1] *= f1; }
  if (last) {
    float4 v0 = (float4){acc[0][0], acc[1][0], acc[2][0], acc[3][0]};
    float4 v1 = (float4){acc[0][1], acc[1][1], acc[2][1], acc[3][1]};
    *(float4*)(out + (size_t)b * N_ + (c << 4) + (og << 2)) = v0;
    *(float4*)(out + (size_t)(b + 1) * N_ + (c << 4) + (og << 2)) = v1;
  } else {
    #pragma unroll
    for (int oo = 0; oo < 4; ++oo)
      *(unsigned int*)&vT[(size_t)((c << 4) + (og << 2) + oo) * B_ + b] =
          pack2(acc[oo][0], acc[oo][1]);
  }
}

// ---- GEMM2 + agreement fused, K=256 split 2x128, LDS-staged + pipelined.
__global__ __launch_bounds__(256) void gemm2_agree(
    const u16* __restrict__ A, const u16* __restrict__ Bt,
    const u16* __restrict__ WtT, float* __restrict__ bij) {
  const int K = 256;
  __shared__ u16 As[2][128 * 32];
  __shared__ u16 Bs[2][128 * 32];
  int tid = threadIdx.x;
  long m0 = (long)blockIdx.x * 128, n0 = (long)blockIdx.y * 128;
  int k0 = blockIdx.z << 7;
  const u16* Ab = A + m0 * K + k0;
  const u16* Bb = Bt + n0 * K + k0;
  int srow = tid >> 2;
  int scol = (tid & 3) << 3;
  int w = tid >> 6, lane = tid & 63;
  int wm = (w >> 1) << 6, wn = (w & 1) << 6;
  int quad = lane >> 4, lrow = lane & 15;
  floatx4 acc[4][4];
  #pragma unroll
  for (int a = 0; a < 4; ++a)
    #pragma unroll
    for (int b = 0; b < 4; ++b) acc[a][b] = (floatx4){0.f, 0.f, 0.f, 0.f};

  uint4 a0 = *(const uint4*)(Ab + (long)srow * K + scol);
  uint4 a1 = *(const uint4*)(Ab + (long)(srow + 64) * K + scol);
  uint4 b0 = *(const uint4*)(Bb + (long)srow * K + scol);
  uint4 b1 = *(const uint4*)(Bb + (long)(srow + 64) * K + scol);

  int p = 0;
  #pragma unroll
  for (int kt = 0; kt < 4; ++kt) {
    ((uint4*)As[p])[tid] = a0;
    ((uint4*)As[p])[tid + 256] = a1;
    ((uint4*)Bs[p])[tid] = b0;
    ((uint4*)Bs[p])[tid + 256] = b1;
    __syncthreads();
    if (kt + 1 < 4) {
      int kk = (kt + 1) << 5;
      a0 = *(const uint4*)(Ab + (long)srow * K + kk + scol);
      a1 = *(const uint4*)(Ab + (long)(srow + 64) * K + kk + scol);
      b0 = *(const uint4*)(Bb + (long)srow * K + kk + scol);
      b1 = *(const uint4*)(Bb + (long)(srow + 64) * K + kk + scol);
    }
    short8 af[4], bfr[4];
    #pragma unroll
    for (int ms = 0; ms < 4; ++ms)
      af[ms] = *(const short8*)&As[p][(wm + ms * 16 + lrow) * 32 + (quad << 3)];
    #pragma unroll
    for (int ns = 0; ns < 4; ++ns)
      bfr[ns] = *(const short8*)&Bs[p][(wn + ns * 16 + lrow) * 32 + (quad << 3)];
    #pragma unroll
    for (int ms = 0; ms < 4; ++ms)
      #pragma unroll
      for (int ns = 0; ns < 4; ++ns)
        acc[ms][ns] = __builtin_amdgcn_mfma_f32_16x16x32_bf16(
            af[ms], bfr[ns], acc[ms][ns], 0, 0, 0);
    p ^= 1;
  }
  // epilogue: per fragment, cols = one capsule c; 16 rows span <=2 routes r.
  #pragma unroll
  for (int ms = 0; ms < 4; ++ms) {
    int rowbase = (int)m0 + wm + ms * 16;          // wave-uniform
    int r_lo = rowbase / I_;
    int r_hi = (rowbase + 15) / I_;
    int bnd = (r_lo + 1) * I_;
    int rowl = rowbase + (quad << 2);
    #pragma unroll
    for (int ns = 0; ns < 4; ++ns) {
      int col = (int)n0 + wn + ns * 16 + lrow;
      uint2 wv = *(const uint2*)&WtT[(size_t)col * K1 + rowl];
      u16 h[4];
      h[0] = (u16)(wv.x & 0xffff); h[1] = (u16)(wv.x >> 16);
      h[2] = (u16)(wv.y & 0xffff); h[3] = (u16)(wv.y >> 16);
      float p0 = 0.f, p1 = 0.f;
      #pragma unroll
      for (int e = 0; e < 4; ++e) {
        float pr = acc[ms][ns][e] * bf2f(h[e]);
        if (rowl + e < bnd) p0 += pr; else p1 += pr;
      }
      #pragma unroll
      for (int off = 32; off > 0; off >>= 1) {
        p0 += __shfl_xor(p0, off);
        p1 += __shfl_xor(p1, off);
      }
      if (lane == 0) {
        int c = col >> 4;
        atomicAdd(&bij[r_lo * C_ + c], p0 * (1.0f / 256.0f));
        atomicAdd(&bij[r_hi * C_ + c], p1 * (1.0f / 256.0f));
      }
    }
  }
}

extern "C" void kernel_launch(void* const* d_in, const int* in_sizes, int n_in,
                              void* d_out, int out_size, void* d_ws, size_t ws_size,
                              hipStream_t stream) {
  const float* X = (const float*)d_in[0];   // fp32 [256,192,20]
  const float* W = (const float*)d_in[1];   // fp32 [192,96,16,20]
  float* out = (float*)d_out;               // fp32 [256,96,16]
  char* ws = (char*)d_ws;
  u16*  WtT = (u16*)(ws);                   // 11,796,480 B
  u16*  Xk  = (u16*)(ws + 11796480);        //  1,966,080 B
  u16*  xT  = (u16*)(ws + 13762560);        //  1,966,080 B
  u16*  vT  = (u16*)(ws + 15728640);        //    786,432 B
  u16*  Pb  = (u16*)(ws + 16515072);        // 20 z x 786,432 B = 15,728,640 B
  float* bij = (float*)(ws + 32243712);     //     73,728 B
  float* cij = (float*)(ws + 32317440);     //     73,728 B

  k_prep<<<23352, 256, 0, stream>>>(W, X, WtT, Xk, xT, bij);

  for (int it = 0; it < 3; ++it) {
    // s partials: M=256,N=1536,K=3840, grid (4 m, 12 n, 20 z), 6 k-iters.
    // it==0: B unscaled; the uniform softmax 1/192 applied in k_redsq.
    gemm1<<<dim3(4, 12, ZSPLIT), 256, 0, stream>>>(Xk, WtT, cij, Pb, it > 0);
    k_redsq<<<dim3(96, 2), 256, 0, stream>>>(
        Pb, out, vT, it == 0 ? (1.0f / 192.0f) : 1.0f, it == 2);
    if (it < 2) {
      gemm2_agree<<<dim3(30, 12, 2), 256, 0, stream>>>(xT, vT, WtT, bij);
      k_cij<<<96, 64, 0, stream>>>(bij, cij);
    }
  }
}

// Round 10
// 167.534 us; speedup vs baseline: 1.0898x; 1.0898x over previous
//
#include <hip/hip_runtime.h>

// DigitCaps dynamic routing, B=256 R=192 C=96 O=16 I=20. fp32 in/out.
// u_hat never materialized. 9 dispatches (the DAG floor):
//   prep: W->WtT bf16 k-major; X->Xk + xT; bij=0 (bij kept C-MAJOR [c][r])
//   gemm1 (x3): 128x128 tile, grid (2,12,20); in-block softmax from c-major
//     bij (coalesced); A staged via async global_load_lds(16B); B staged via
//     reg prefetch + softmax scale at LDS-write; double LDS, 1 barrier/iter;
//     partials stored transposed bf16 P^T[z][n][b]
//   redsq (x3): coalesced split-K reduce + squash -> vT / out
//   gemm2_agree (x2): FULLY async-staged (global_load_lds A+B); Z-tile in
//     regs; agreement in epilogue vs WtT, atomicAdd bij[c][r]. K=256 split 2.

#define R_ 192
#define C_ 96
#define O_ 16
#define I_ 20
#define B_ 256
#define K1 3840   // R*I
#define N_ 1536   // C*O
#define ZSPLIT 20
#define STILE 393216  // N_*B_ elements per z-slice

typedef unsigned short u16;
typedef __attribute__((ext_vector_type(8))) short short8;
typedef __attribute__((ext_vector_type(4))) float floatx4;

__device__ inline float bf2f(u16 h) {
  union { unsigned int u; float f; } x; x.u = ((unsigned int)h) << 16; return x.f;
}
__device__ inline u16 f2bf(float f) {
  union { float f; unsigned int u; } x; x.f = f;
  unsigned int r = x.u + 0x7FFFu + ((x.u >> 16) & 1u);
  return (u16)(r >> 16);
}
__device__ inline unsigned int pack2(float a, float b) {
  return (unsigned int)f2bf(a) | ((unsigned int)f2bf(b) << 16);
}
// async 16B/lane global->LDS; lds base must be wave-uniform (lane scatters +16B)
__device__ inline void async16(const u16* g, u16* l) {
  __builtin_amdgcn_global_load_lds(
      (__attribute__((address_space(1))) void*)(unsigned long long)g,
      (__attribute__((address_space(3))) void*)(unsigned int)(unsigned long long)l,
      16, 0, 0);
}

// ---- fused prep: WtT gather (5760 blocks, 4 elems/thr); X cast+transpose
// (240); bij=0 c-major (18)
__global__ void k_prep(const float* __restrict__ W, const float* __restrict__ X,
                       u16* __restrict__ WtT, u16* __restrict__ Xk,
                       u16* __restrict__ xT, float* __restrict__ bij) {
  int bid = blockIdx.x;
  if (bid < 5760) {
    int t = (bid * 256 + threadIdx.x) << 2;    // over N_*K1; 4-group stays in one n
    int n = t / K1, k = t - n * K1;
    int c = n >> 4, o = n & 15;
    const float* Wn = W + (size_t)(c * O_ + o) * I_;
    u16 h[4];
    #pragma unroll
    for (int e = 0; e < 4; ++e) {
      int ke = k + e, r = ke / I_, i = ke - r * I_;
      h[e] = f2bf(Wn[(size_t)r * (C_ * O_ * I_) + i]);
    }
    ushort4 o4; o4.x = h[0]; o4.y = h[1]; o4.z = h[2]; o4.w = h[3];
    *(ushort4*)&WtT[t] = o4;
  } else if (bid < 6000) {
    __shared__ u16 tile[64][72];
    int idx = bid - 5760;
    int kb = (idx % 60) << 6, bb = (idx / 60) << 6;
    int brow = threadIdx.x >> 4;          // 0..15
    int kq = (threadIdx.x & 15) << 2;     // 0..60 step 4
    #pragma unroll
    for (int p = 0; p < 4; ++p) {
      int bl = p * 16 + brow;
      float4 v = *(const float4*)(X + (size_t)(bb + bl) * K1 + kb + kq);
      ushort4 h;
      h.x = f2bf(v.x); h.y = f2bf(v.y); h.z = f2bf(v.z); h.w = f2bf(v.w);
      *(ushort4*)(Xk + (size_t)(bb + bl) * K1 + kb + kq) = h;
      tile[kq + 0][bl] = h.x;
      tile[kq + 1][bl] = h.y;
      tile[kq + 2][bl] = h.z;
      tile[kq + 3][bl] = h.w;
    }
    __syncthreads();
    int kr = threadIdx.x >> 3;            // 0..31
    int bq = (threadIdx.x & 7) << 3;      // 0..56 step 8
    #pragma unroll
    for (int q = 0; q < 2; ++q) {
      int kl = q * 32 + kr;
      *(uint4*)(xT + (size_t)(kb + kl) * B_ + bb + bq) = *(const uint4*)&tile[kl][bq];
    }
  } else {
    int t = ((bid - 6000) * 256 + threadIdx.x) << 2;  // bij: 18,432 floats
    if (t < R_ * C_) *(float4*)&bij[t] = (float4){0.f, 0.f, 0.f, 0.f};
  }
}

// scale 8 k-contiguous bf16 (global k = kg..kg+7) by softmax row(s)
__device__ inline uint4 scale_b8(uint4 raw, int kg, const float* smrow) {
  int r0 = kg / I_;
  int bnd = (r0 + 1) * I_ - kg;                // elements j<bnd use r0
  float s0 = smrow[r0];
  float s1 = smrow[(r0 + 1 < R_) ? r0 + 1 : R_ - 1];
  union { uint4 q; u16 h[8]; } u; u.q = raw;
  #pragma unroll
  for (int j = 0; j < 8; ++j)
    u.h[j] = f2bf(bf2f(u.h[j]) * ((j < bnd) ? s0 : s1));
  return u.q;
}

// ---- GEMM1: P^T[z][n][b] bf16 = (Xk[256,3840] x (c*WtT)[1536,3840]^T),
// k-chunk z. 128x128 tile, BK=32, 4 waves of 64x64, grid (2,12,20).
// A staged async (global_load_lds), B via reg prefetch + scale at LDS-write.
__global__ __launch_bounds__(256) void gemm1(
    const u16* __restrict__ A, const u16* __restrict__ Bt,
    const float* __restrict__ bij, u16* __restrict__ P) {
  __shared__ u16 As[2][128 * 32];
  __shared__ u16 Bs[2][128 * 32];
  __shared__ float sm[8][192];
  int tid = threadIdx.x;
  // --- softmax table (8 capsules of this n-tile), coalesced c-major reads
  {
    int cg = tid >> 5, lr = tid & 31;
    int c = (blockIdx.y << 3) + cg;
    float e[6]; float mx = -1e30f;
    #pragma unroll
    for (int j = 0; j < 6; ++j) {
      e[j] = bij[c * R_ + lr + (j << 5)];
      mx = fmaxf(mx, e[j]);
    }
    #pragma unroll
    for (int off = 16; off > 0; off >>= 1) mx = fmaxf(mx, __shfl_xor(mx, off));
    float sum = 0.f;
    #pragma unroll
    for (int j = 0; j < 6; ++j) { e[j] = expf(e[j] - mx); sum += e[j]; }
    #pragma unroll
    for (int off = 16; off > 0; off >>= 1) sum += __shfl_xor(sum, off);
    float inv = 1.0f / sum;
    #pragma unroll
    for (int j = 0; j < 6; ++j) sm[cg][lr + (j << 5)] = e[j] * inv;
  }

  long m0 = (long)blockIdx.x * 128, n0 = (long)blockIdx.y * 128;
  int k0 = blockIdx.z * 192;
  const u16* Ab = A + m0 * K1 + k0;
  const u16* Bb = Bt + n0 * K1 + k0;
  int srow = tid >> 2;              // 0..63 (+64 for second row)
  int scol = (tid & 3) << 3;        // 0,8,16,24
  int w = tid >> 6, lane = tid & 63;
  int wm = (w >> 1) << 6, wn = (w & 1) << 6;
  int quad = lane >> 4, lrow = lane & 15;
  int cl0 = srow >> 4;              // c_local of B row srow (0..3)
  int wb = w << 9;                  // wave-uniform LDS base (u16 elems)
  const u16* Ag0 = Ab + (long)srow * K1 + scol;
  const u16* Ag1 = Ab + (long)(srow + 64) * K1 + scol;
  floatx4 acc[4][4];
  #pragma unroll
  for (int a = 0; a < 4; ++a)
    #pragma unroll
    for (int b = 0; b < 4; ++b) acc[a][b] = (floatx4){0.f, 0.f, 0.f, 0.f};

  // kt=0: async A into buf0, raw B into regs
  async16(Ag0, &As[0][wb]);
  async16(Ag1, &As[0][2048 + wb]);
  uint4 b0 = *(const uint4*)(Bb + (long)srow * K1 + scol);
  uint4 b1 = *(const uint4*)(Bb + (long)(srow + 64) * K1 + scol);
  __syncthreads();                   // sm table visible (also drains async)

  int p = 0;
  for (int kt = 0; kt < 6; ++kt) {
    int kg = k0 + (kt << 5) + scol;
    ((uint4*)Bs[p])[tid] = scale_b8(b0, kg, &sm[cl0][0]);
    ((uint4*)Bs[p])[tid + 256] = scale_b8(b1, kg, &sm[cl0 + 4][0]);
    __syncthreads();                 // As[p] async complete + Bs[p] visible
    if (kt + 1 < 6) {                // prefetch escapes the barrier drain
      int kk = (kt + 1) << 5;
      async16(Ag0 + kk, &As[p ^ 1][wb]);
      async16(Ag1 + kk, &As[p ^ 1][2048 + wb]);
      b0 = *(const uint4*)(Bb + (long)srow * K1 + kk + scol);
      b1 = *(const uint4*)(Bb + (long)(srow + 64) * K1 + kk + scol);
    }
    short8 af[4], bfr[4];
    #pragma unroll
    for (int ms = 0; ms < 4; ++ms)
      af[ms] = *(const short8*)&As[p][(wm + ms * 16 + lrow) * 32 + (quad << 3)];
    #pragma unroll
    for (int ns = 0; ns < 4; ++ns)
      bfr[ns] = *(const short8*)&Bs[p][(wn + ns * 16 + lrow) * 32 + (quad << 3)];
    #pragma unroll
    for (int ms = 0; ms < 4; ++ms)
      #pragma unroll
      for (int ns = 0; ns < 4; ++ns)
        acc[ms][ns] = __builtin_amdgcn_mfma_f32_16x16x32_bf16(
            af[ms], bfr[ns], acc[ms][ns], 0, 0, 0);
    p ^= 1;
  }
  // transposed bf16 store: P[z][n*256 + b]; lane holds 4 consecutive b
  size_t zb = (size_t)blockIdx.z * (size_t)STILE;
  #pragma unroll
  for (int ms = 0; ms < 4; ++ms)
    #pragma unroll
    for (int ns = 0; ns < 4; ++ns) {
      int b = (int)m0 + wm + ms * 16 + (quad << 2);
      int n = (int)n0 + wn + ns * 16 + lrow;
      uint2 pk;
      pk.x = pack2(acc[ms][ns][0], acc[ms][ns][1]);
      pk.y = pack2(acc[ms][ns][2], acc[ms][ns][3]);
      *(uint2*)&P[zb + (size_t)n * B_ + b] = pk;
    }
}

// ---- fused split-K reduce + squash, reading P^T[z][n][b] bf16.
// grid (96 c, 2 b-halves), block 256 = 4 o-groups x 64 lanes; 2 b per lane.
__global__ void k_redsq(const u16* __restrict__ P, float* __restrict__ out,
                        u16* __restrict__ vT, int last) {
  __shared__ float nsq_l[4][128];
  int c = blockIdx.x, bh = blockIdx.y;
  int lane = threadIdx.x & 63, og = threadIdx.x >> 6;
  int bi = (lane << 1);                  // local b index (0..126 step 2)
  int b = (bh << 7) + bi;
  float acc[4][2];
  #pragma unroll
  for (int oo = 0; oo < 4; ++oo) { acc[oo][0] = 0.f; acc[oo][1] = 0.f; }
  for (int z = 0; z < ZSPLIT; ++z) {
    size_t base = (size_t)z * STILE + (size_t)((c << 4) + (og << 2)) * B_ + b;
    #pragma unroll
    for (int oo = 0; oo < 4; ++oo) {
      unsigned int u = *(const unsigned int*)&P[base + (size_t)oo * B_];
      acc[oo][0] += bf2f((u16)(u & 0xffff));
      acc[oo][1] += bf2f((u16)(u >> 16));
    }
  }
  float q0 = 0.f, q1 = 0.f;
  #pragma unroll
  for (int oo = 0; oo < 4; ++oo) {
    q0 += acc[oo][0] * acc[oo][0];
    q1 += acc[oo][1] * acc[oo][1];
  }
  nsq_l[og][bi] = q0;
  nsq_l[og][bi + 1] = q1;
  __syncthreads();
  float n0 = nsq_l[0][bi] + nsq_l[1][bi] + nsq_l[2][bi] + nsq_l[3][bi];
  float n1 = nsq_l[0][bi + 1] + nsq_l[1][bi + 1] + nsq_l[2][bi + 1] + nsq_l[3][bi + 1];
  float f0 = n0 / ((1.0f + n0) * sqrtf(n0));
  float f1 = n1 / ((1.0f + n1) * sqrtf(n1));
  #pragma unroll
  for (int oo = 0; oo < 4; ++oo) { acc[oo][0] *= f0; acc[oo][1] *= f1; }
  if (last) {
    float4 v0 = (float4){acc[0][0], acc[1][0], acc[2][0], acc[3][0]};
    float4 v1 = (float4){acc[0][1], acc[1][1], acc[2][1], acc[3][1]};
    *(float4*)(out + (size_t)b * N_ + (c << 4) + (og << 2)) = v0;
    *(float4*)(out + (size_t)(b + 1) * N_ + (c << 4) + (og << 2)) = v1;
  } else {
    #pragma unroll
    for (int oo = 0; oo < 4; ++oo)
      *(unsigned int*)&vT[(size_t)((c << 4) + (og << 2) + oo) * B_ + b] =
          pack2(acc[oo][0], acc[oo][1]);
  }
}

// ---- GEMM2 + agreement fused, K=256 split 2x128, fully async staging.
__global__ __launch_bounds__(256) void gemm2_agree(
    const u16* __restrict__ A, const u16* __restrict__ Bt,
    const u16* __restrict__ WtT, float* __restrict__ bij) {
  const int K = 256;
  __shared__ u16 As[2][128 * 32];
  __shared__ u16 Bs[2][128 * 32];
  int tid = threadIdx.x;
  long m0 = (long)blockIdx.x * 128, n0 = (long)blockIdx.y * 128;
  int k0 = blockIdx.z << 7;
  const u16* Ab = A + m0 * K + k0;
  const u16* Bb = Bt + n0 * K + k0;
  int srow = tid >> 2;
  int scol = (tid & 3) << 3;
  int w = tid >> 6, lane = tid & 63;
  int wm = (w >> 1) << 6, wn = (w & 1) << 6;
  int quad = lane >> 4, lrow = lane & 15;
  int wb = w << 9;                  // wave-uniform LDS base (u16 elems)
  const u16* Ag0 = Ab + (long)srow * K + scol;
  const u16* Ag1 = Ab + (long)(srow + 64) * K + scol;
  const u16* Bg0 = Bb + (long)srow * K + scol;
  const u16* Bg1 = Bb + (long)(srow + 64) * K + scol;
  floatx4 acc[4][4];
  #pragma unroll
  for (int a = 0; a < 4; ++a)
    #pragma unroll
    for (int b = 0; b < 4; ++b) acc[a][b] = (floatx4){0.f, 0.f, 0.f, 0.f};

  async16(Ag0, &As[0][wb]);
  async16(Ag1, &As[0][2048 + wb]);
  async16(Bg0, &Bs[0][wb]);
  async16(Bg1, &Bs[0][2048 + wb]);

  int p = 0;
  #pragma unroll
  for (int kt = 0; kt < 4; ++kt) {
    __syncthreads();                 // buf p complete
    if (kt + 1 < 4) {                // async prefetch escapes the drain
      int kk = (kt + 1) << 5;
      async16(Ag0 + kk, &As[p ^ 1][wb]);
      async16(Ag1 + kk, &As[p ^ 1][2048 + wb]);
      async16(Bg0 + kk, &Bs[p ^ 1][wb]);
      async16(Bg1 + kk, &Bs[p ^ 1][2048 + wb]);
    }
    short8 af[4], bfr[4];
    #pragma unroll
    for (int ms = 0; ms < 4; ++ms)
      af[ms] = *(const short8*)&As[p][(wm + ms * 16 + lrow) * 32 + (quad << 3)];
    #pragma unroll
    for (int ns = 0; ns < 4; ++ns)
      bfr[ns] = *(const short8*)&Bs[p][(wn + ns * 16 + lrow) * 32 + (quad << 3)];
    #pragma unroll
    for (int ms = 0; ms < 4; ++ms)
      #pragma unroll
      for (int ns = 0; ns < 4; ++ns)
        acc[ms][ns] = __builtin_amdgcn_mfma_f32_16x16x32_bf16(
            af[ms], bfr[ns], acc[ms][ns], 0, 0, 0);
    p ^= 1;
  }
  // epilogue: per fragment, cols = one capsule c; 16 rows span <=2 routes r.
  #pragma unroll
  for (int ms = 0; ms < 4; ++ms) {
    int rowbase = (int)m0 + wm + ms * 16;          // wave-uniform
    int r_lo = rowbase / I_;
    int r_hi = (rowbase + 15) / I_;
    int bnd = (r_lo + 1) * I_;
    int rowl = rowbase + (quad << 2);
    #pragma unroll
    for (int ns = 0; ns < 4; ++ns) {
      int col = (int)n0 + wn + ns * 16 + lrow;
      uint2 wv = *(const uint2*)&WtT[(size_t)col * K1 + rowl];
      u16 h[4];
      h[0] = (u16)(wv.x & 0xffff); h[1] = (u16)(wv.x >> 16);
      h[2] = (u16)(wv.y & 0xffff); h[3] = (u16)(wv.y >> 16);
      float p0 = 0.f, p1 = 0.f;
      #pragma unroll
      for (int e = 0; e < 4; ++e) {
        float pr = acc[ms][ns][e] * bf2f(h[e]);
        if (rowl + e < bnd) p0 += pr; else p1 += pr;
      }
      #pragma unroll
      for (int off = 32; off > 0; off >>= 1) {
        p0 += __shfl_xor(p0, off);
        p1 += __shfl_xor(p1, off);
      }
      if (lane == 0) {
        int c = col >> 4;
        atomicAdd(&bij[c * R_ + r_lo], p0 * (1.0f / 256.0f));
        atomicAdd(&bij[c * R_ + r_hi], p1 * (1.0f / 256.0f));
      }
    }
  }
}

extern "C" void kernel_launch(void* const* d_in, const int* in_sizes, int n_in,
                              void* d_out, int out_size, void* d_ws, size_t ws_size,
                              hipStream_t stream) {
  const float* X = (const float*)d_in[0];   // fp32 [256,192,20]
  const float* W = (const float*)d_in[1];   // fp32 [192,96,16,20]
  float* out = (float*)d_out;               // fp32 [256,96,16]
  char* ws = (char*)d_ws;
  u16*  WtT = (u16*)(ws);                   // 11,796,480 B
  u16*  Xk  = (u16*)(ws + 11796480);        //  1,966,080 B
  u16*  xT  = (u16*)(ws + 13762560);        //  1,966,080 B
  u16*  vT  = (u16*)(ws + 15728640);        //    786,432 B
  u16*  Pb  = (u16*)(ws + 16515072);        // 20 z x 786,432 B = 15,728,640 B
  float* bij = (float*)(ws + 32243712);     //     73,728 B (c-major [c][r])

  k_prep<<<6018, 256, 0, stream>>>(W, X, WtT, Xk, xT, bij);

  for (int it = 0; it < 3; ++it) {
    // s partials: M=256,N=1536,K=3840, grid (2,12,20), 6 k-iters.
    // iter 0: bij==0 -> softmax table is uniform 1/192 automatically.
    gemm1<<<dim3(2, 12, ZSPLIT), 256, 0, stream>>>(Xk, WtT, bij, Pb);
    k_redsq<<<dim3(96, 2), 256, 0, stream>>>(Pb, out, vT, it == 2);
    if (it < 2)
      gemm2_agree<<<dim3(30, 12, 2), 256, 0, stream>>>(xT, vT, WtT, bij);
  }
}

// Round 11
// 164.656 us; speedup vs baseline: 1.1088x; 1.0175x over previous
//
#include <hip/hip_runtime.h>

// DigitCaps dynamic routing, B=256 R=192 C=96 O=16 I=20. fp32 in/out.
// u_hat never materialized. 9 dispatches (DAG floor):
//   prep: W->WtT bf16 k-major; X->Xk + xT; bij=0 (bij C-MAJOR [c][r])
//   gemm1 (x3): 128x128 tile, grid (2,12,20); A async global_load_lds(16B);
//     B reg-prefetch + softmax scale at LDS-write (it0: no scale, 1/192
//     folded into redsq preScale); double LDS, 1 barrier/iter; partials
//     stored transposed bf16 P^T[z][n][b]
//   redsq (x3): grid (96,4) all-CU; split-K reduce + squash -> vT / out
//   gemm2_agree (x2): K=256 single-split (epilogue executed once per tile),
//     fully async staging; agreement in epilogue vs WtT, atomicAdd bij[c][r]

#define R_ 192
#define C_ 96
#define O_ 16
#define I_ 20
#define B_ 256
#define K1 3840   // R*I
#define N_ 1536   // C*O
#define ZSPLIT 20
#define STILE 393216  // N_*B_ elements per z-slice

typedef unsigned short u16;
typedef __attribute__((ext_vector_type(8))) short short8;
typedef __attribute__((ext_vector_type(4))) float floatx4;

__device__ inline float bf2f(u16 h) {
  union { unsigned int u; float f; } x; x.u = ((unsigned int)h) << 16; return x.f;
}
__device__ inline u16 f2bf(float f) {
  union { float f; unsigned int u; } x; x.f = f;
  unsigned int r = x.u + 0x7FFFu + ((x.u >> 16) & 1u);
  return (u16)(r >> 16);
}
__device__ inline unsigned int pack2(float a, float b) {
  return (unsigned int)f2bf(a) | ((unsigned int)f2bf(b) << 16);
}
// async 16B/lane global->LDS; lds base must be wave-uniform (lane scatters +16B)
__device__ inline void async16(const u16* g, u16* l) {
  __builtin_amdgcn_global_load_lds(
      (__attribute__((address_space(1))) void*)(unsigned long long)g,
      (__attribute__((address_space(3))) void*)(unsigned int)(unsigned long long)l,
      16, 0, 0);
}

// ---- fused prep: WtT gather (5760 blocks, 4 elems/thr); X cast+transpose
// (240); bij=0 c-major (18)
__global__ void k_prep(const float* __restrict__ W, const float* __restrict__ X,
                       u16* __restrict__ WtT, u16* __restrict__ Xk,
                       u16* __restrict__ xT, float* __restrict__ bij) {
  int bid = blockIdx.x;
  if (bid < 5760) {
    int t = (bid * 256 + threadIdx.x) << 2;    // over N_*K1; 4-group stays in one n
    int n = t / K1, k = t - n * K1;
    int c = n >> 4, o = n & 15;
    const float* Wn = W + (size_t)(c * O_ + o) * I_;
    u16 h[4];
    #pragma unroll
    for (int e = 0; e < 4; ++e) {
      int ke = k + e, r = ke / I_, i = ke - r * I_;
      h[e] = f2bf(Wn[(size_t)r * (C_ * O_ * I_) + i]);
    }
    ushort4 o4; o4.x = h[0]; o4.y = h[1]; o4.z = h[2]; o4.w = h[3];
    *(ushort4*)&WtT[t] = o4;
  } else if (bid < 6000) {
    __shared__ u16 tile[64][72];
    int idx = bid - 5760;
    int kb = (idx % 60) << 6, bb = (idx / 60) << 6;
    int brow = threadIdx.x >> 4;          // 0..15
    int kq = (threadIdx.x & 15) << 2;     // 0..60 step 4
    #pragma unroll
    for (int p = 0; p < 4; ++p) {
      int bl = p * 16 + brow;
      float4 v = *(const float4*)(X + (size_t)(bb + bl) * K1 + kb + kq);
      ushort4 h;
      h.x = f2bf(v.x); h.y = f2bf(v.y); h.z = f2bf(v.z); h.w = f2bf(v.w);
      *(ushort4*)(Xk + (size_t)(bb + bl) * K1 + kb + kq) = h;
      tile[kq + 0][bl] = h.x;
      tile[kq + 1][bl] = h.y;
      tile[kq + 2][bl] = h.z;
      tile[kq + 3][bl] = h.w;
    }
    __syncthreads();
    int kr = threadIdx.x >> 3;            // 0..31
    int bq = (threadIdx.x & 7) << 3;      // 0..56 step 8
    #pragma unroll
    for (int q = 0; q < 2; ++q) {
      int kl = q * 32 + kr;
      *(uint4*)(xT + (size_t)(kb + kl) * B_ + bb + bq) = *(const uint4*)&tile[kl][bq];
    }
  } else {
    int t = ((bid - 6000) * 256 + threadIdx.x) << 2;  // bij: 18,432 floats
    if (t < R_ * C_) *(float4*)&bij[t] = (float4){0.f, 0.f, 0.f, 0.f};
  }
}

// scale 8 k-contiguous bf16 (global k = kg..kg+7) by softmax row(s)
__device__ inline uint4 scale_b8(uint4 raw, int kg, const float* smrow) {
  int r0 = kg / I_;
  int bnd = (r0 + 1) * I_ - kg;                // elements j<bnd use r0
  float s0 = smrow[r0];
  float s1 = smrow[(r0 + 1 < R_) ? r0 + 1 : R_ - 1];
  union { uint4 q; u16 h[8]; } u; u.q = raw;
  #pragma unroll
  for (int j = 0; j < 8; ++j)
    u.h[j] = f2bf(bf2f(u.h[j]) * ((j < bnd) ? s0 : s1));
  return u.q;
}

// ---- GEMM1: P^T[z][n][b] bf16 = (Xk[256,3840] x (c*WtT)[1536,3840]^T),
// k-chunk z. 128x128 tile, BK=32, 4 waves of 64x64, grid (2,12,20).
// A staged async; B reg prefetch (+scale at LDS-write when doScale).
__global__ __launch_bounds__(256) void gemm1(
    const u16* __restrict__ A, const u16* __restrict__ Bt,
    const float* __restrict__ bij, u16* __restrict__ P, int doScale) {
  __shared__ u16 As[2][128 * 32];
  __shared__ u16 Bs[2][128 * 32];
  __shared__ float sm[8][192];
  int tid = threadIdx.x;
  if (doScale) {  // softmax table (8 capsules), coalesced c-major reads
    int cg = tid >> 5, lr = tid & 31;
    int c = (blockIdx.y << 3) + cg;
    float e[6]; float mx = -1e30f;
    #pragma unroll
    for (int j = 0; j < 6; ++j) {
      e[j] = bij[c * R_ + lr + (j << 5)];
      mx = fmaxf(mx, e[j]);
    }
    #pragma unroll
    for (int off = 16; off > 0; off >>= 1) mx = fmaxf(mx, __shfl_xor(mx, off));
    float sum = 0.f;
    #pragma unroll
    for (int j = 0; j < 6; ++j) { e[j] = expf(e[j] - mx); sum += e[j]; }
    #pragma unroll
    for (int off = 16; off > 0; off >>= 1) sum += __shfl_xor(sum, off);
    float inv = 1.0f / sum;
    #pragma unroll
    for (int j = 0; j < 6; ++j) sm[cg][lr + (j << 5)] = e[j] * inv;
  }

  long m0 = (long)blockIdx.x * 128, n0 = (long)blockIdx.y * 128;
  int k0 = blockIdx.z * 192;
  const u16* Ab = A + m0 * K1 + k0;
  const u16* Bb = Bt + n0 * K1 + k0;
  int srow = tid >> 2;              // 0..63 (+64 for second row)
  int scol = (tid & 3) << 3;        // 0,8,16,24
  int w = tid >> 6, lane = tid & 63;
  int wm = (w >> 1) << 6, wn = (w & 1) << 6;
  int quad = lane >> 4, lrow = lane & 15;
  int cl0 = srow >> 4;              // c_local of B row srow (0..3)
  int wb = w << 9;                  // wave-uniform LDS base (u16 elems)
  const u16* Ag0 = Ab + (long)srow * K1 + scol;
  const u16* Ag1 = Ab + (long)(srow + 64) * K1 + scol;
  floatx4 acc[4][4];
  #pragma unroll
  for (int a = 0; a < 4; ++a)
    #pragma unroll
    for (int b = 0; b < 4; ++b) acc[a][b] = (floatx4){0.f, 0.f, 0.f, 0.f};

  // kt=0: async A into buf0, raw B into regs
  async16(Ag0, &As[0][wb]);
  async16(Ag1, &As[0][2048 + wb]);
  uint4 b0 = *(const uint4*)(Bb + (long)srow * K1 + scol);
  uint4 b1 = *(const uint4*)(Bb + (long)(srow + 64) * K1 + scol);
  __syncthreads();                   // sm visible + As[0] async drained

  int p = 0;
  for (int kt = 0; kt < 6; ++kt) {
    if (doScale) {
      int kg = k0 + (kt << 5) + scol;
      ((uint4*)Bs[p])[tid] = scale_b8(b0, kg, &sm[cl0][0]);
      ((uint4*)Bs[p])[tid + 256] = scale_b8(b1, kg, &sm[cl0 + 4][0]);
    } else {
      ((uint4*)Bs[p])[tid] = b0;
      ((uint4*)Bs[p])[tid + 256] = b1;
    }
    __syncthreads();                 // As[p] async complete + Bs[p] visible
    if (kt + 1 < 6) {                // prefetch escapes the barrier drain
      int kk = (kt + 1) << 5;
      async16(Ag0 + kk, &As[p ^ 1][wb]);
      async16(Ag1 + kk, &As[p ^ 1][2048 + wb]);
      b0 = *(const uint4*)(Bb + (long)srow * K1 + kk + scol);
      b1 = *(const uint4*)(Bb + (long)(srow + 64) * K1 + kk + scol);
    }
    short8 af[4], bfr[4];
    #pragma unroll
    for (int ms = 0; ms < 4; ++ms)
      af[ms] = *(const short8*)&As[p][(wm + ms * 16 + lrow) * 32 + (quad << 3)];
    #pragma unroll
    for (int ns = 0; ns < 4; ++ns)
      bfr[ns] = *(const short8*)&Bs[p][(wn + ns * 16 + lrow) * 32 + (quad << 3)];
    #pragma unroll
    for (int ms = 0; ms < 4; ++ms)
      #pragma unroll
      for (int ns = 0; ns < 4; ++ns)
        acc[ms][ns] = __builtin_amdgcn_mfma_f32_16x16x32_bf16(
            af[ms], bfr[ns], acc[ms][ns], 0, 0, 0);
    p ^= 1;
  }
  // transposed bf16 store: P[z][n*256 + b]; lane holds 4 consecutive b
  size_t zb = (size_t)blockIdx.z * (size_t)STILE;
  #pragma unroll
  for (int ms = 0; ms < 4; ++ms)
    #pragma unroll
    for (int ns = 0; ns < 4; ++ns) {
      int b = (int)m0 + wm + ms * 16 + (quad << 2);
      int n = (int)n0 + wn + ns * 16 + lrow;
      uint2 pk;
      pk.x = pack2(acc[ms][ns][0], acc[ms][ns][1]);
      pk.y = pack2(acc[ms][ns][2], acc[ms][ns][3]);
      *(uint2*)&P[zb + (size_t)n * B_ + b] = pk;
    }
}

// ---- fused split-K reduce + squash, reading P^T[z][n][b] bf16.
// grid (96 c, 4 b-quarters) = 384 blocks (all CUs); block 256 = 4 o-groups
// x 64 lanes; 1 b per lane.
__global__ void k_redsq(const u16* __restrict__ P, float* __restrict__ out,
                        u16* __restrict__ vT, float preScale, int last) {
  __shared__ float nsq_l[4][64];
  int c = blockIdx.x, bh = blockIdx.y;
  int lane = threadIdx.x & 63, og = threadIdx.x >> 6;
  int b = (bh << 6) + lane;
  int n0 = (c << 4) + (og << 2);
  float acc[4];
  #pragma unroll
  for (int oo = 0; oo < 4; ++oo) acc[oo] = 0.f;
  #pragma unroll
  for (int z = 0; z < ZSPLIT; ++z) {
    size_t base = (size_t)z * STILE + (size_t)n0 * B_ + b;
    #pragma unroll
    for (int oo = 0; oo < 4; ++oo)
      acc[oo] += bf2f(P[base + (size_t)oo * B_]);
  }
  #pragma unroll
  for (int oo = 0; oo < 4; ++oo) acc[oo] *= preScale;
  float q = acc[0] * acc[0] + acc[1] * acc[1] + acc[2] * acc[2] + acc[3] * acc[3];
  nsq_l[og][lane] = q;
  __syncthreads();
  float nsq = nsq_l[0][lane] + nsq_l[1][lane] + nsq_l[2][lane] + nsq_l[3][lane];
  float f = nsq / ((1.0f + nsq) * sqrtf(nsq));
  #pragma unroll
  for (int oo = 0; oo < 4; ++oo) acc[oo] *= f;
  if (last) {
    *(float4*)(out + (size_t)b * N_ + n0) = (float4){acc[0], acc[1], acc[2], acc[3]};
  } else {
    #pragma unroll
    for (int oo = 0; oo < 4; ++oo)
      vT[(size_t)(n0 + oo) * B_ + b] = f2bf(acc[oo]);
  }
}

// ---- GEMM2 + agreement fused, K=256 single split, fully async staging.
// Epilogue (the expensive part) executed ONCE per tile.
__global__ __launch_bounds__(256) void gemm2_agree(
    const u16* __restrict__ A, const u16* __restrict__ Bt,
    const u16* __restrict__ WtT, float* __restrict__ bij) {
  const int K = 256;
  __shared__ u16 As[2][128 * 32];
  __shared__ u16 Bs[2][128 * 32];
  int tid = threadIdx.x;
  long m0 = (long)blockIdx.x * 128, n0 = (long)blockIdx.y * 128;
  const u16* Ab = A + m0 * K;
  const u16* Bb = Bt + n0 * K;
  int srow = tid >> 2;
  int scol = (tid & 3) << 3;
  int w = tid >> 6, lane = tid & 63;
  int wm = (w >> 1) << 6, wn = (w & 1) << 6;
  int quad = lane >> 4, lrow = lane & 15;
  int wb = w << 9;                  // wave-uniform LDS base (u16 elems)
  const u16* Ag0 = Ab + (long)srow * K + scol;
  const u16* Ag1 = Ab + (long)(srow + 64) * K + scol;
  const u16* Bg0 = Bb + (long)srow * K + scol;
  const u16* Bg1 = Bb + (long)(srow + 64) * K + scol;
  floatx4 acc[4][4];
  #pragma unroll
  for (int a = 0; a < 4; ++a)
    #pragma unroll
    for (int b = 0; b < 4; ++b) acc[a][b] = (floatx4){0.f, 0.f, 0.f, 0.f};

  async16(Ag0, &As[0][wb]);
  async16(Ag1, &As[0][2048 + wb]);
  async16(Bg0, &Bs[0][wb]);
  async16(Bg1, &Bs[0][2048 + wb]);

  int p = 0;
  #pragma unroll
  for (int kt = 0; kt < 8; ++kt) {
    __syncthreads();                 // buf p complete
    if (kt + 1 < 8) {                // async prefetch escapes the drain
      int kk = (kt + 1) << 5;
      async16(Ag0 + kk, &As[p ^ 1][wb]);
      async16(Ag1 + kk, &As[p ^ 1][2048 + wb]);
      async16(Bg0 + kk, &Bs[p ^ 1][wb]);
      async16(Bg1 + kk, &Bs[p ^ 1][2048 + wb]);
    }
    short8 af[4], bfr[4];
    #pragma unroll
    for (int ms = 0; ms < 4; ++ms)
      af[ms] = *(const short8*)&As[p][(wm + ms * 16 + lrow) * 32 + (quad << 3)];
    #pragma unroll
    for (int ns = 0; ns < 4; ++ns)
      bfr[ns] = *(const short8*)&Bs[p][(wn + ns * 16 + lrow) * 32 + (quad << 3)];
    #pragma unroll
    for (int ms = 0; ms < 4; ++ms)
      #pragma unroll
      for (int ns = 0; ns < 4; ++ns)
        acc[ms][ns] = __builtin_amdgcn_mfma_f32_16x16x32_bf16(
            af[ms], bfr[ns], acc[ms][ns], 0, 0, 0);
    p ^= 1;
  }
  // epilogue: per fragment, cols = one capsule c; 16 rows span <=2 routes r.
  #pragma unroll
  for (int ms = 0; ms < 4; ++ms) {
    int rowbase = (int)m0 + wm + ms * 16;          // wave-uniform
    int r_lo = rowbase / I_;
    int r_hi = (rowbase + 15) / I_;
    int bnd = (r_lo + 1) * I_;
    int rowl = rowbase + (quad << 2);
    #pragma unroll
    for (int ns = 0; ns < 4; ++ns) {
      int col = (int)n0 + wn + ns * 16 + lrow;
      uint2 wv = *(const uint2*)&WtT[(size_t)col * K1 + rowl];
      u16 h[4];
      h[0] = (u16)(wv.x & 0xffff); h[1] = (u16)(wv.x >> 16);
      h[2] = (u16)(wv.y & 0xffff); h[3] = (u16)(wv.y >> 16);
      float p0 = 0.f, p1 = 0.f;
      #pragma unroll
      for (int e = 0; e < 4; ++e) {
        float pr = acc[ms][ns][e] * bf2f(h[e]);
        if (rowl + e < bnd) p0 += pr; else p1 += pr;
      }
      #pragma unroll
      for (int off = 32; off > 0; off >>= 1) {
        p0 += __shfl_xor(p0, off);
        p1 += __shfl_xor(p1, off);
      }
      if (lane == 0) {
        int c = col >> 4;
        atomicAdd(&bij[c * R_ + r_lo], p0 * (1.0f / 256.0f));
        atomicAdd(&bij[c * R_ + r_hi], p1 * (1.0f / 256.0f));
      }
    }
  }
}

extern "C" void kernel_launch(void* const* d_in, const int* in_sizes, int n_in,
                              void* d_out, int out_size, void* d_ws, size_t ws_size,
                              hipStream_t stream) {
  const float* X = (const float*)d_in[0];   // fp32 [256,192,20]
  const float* W = (const float*)d_in[1];   // fp32 [192,96,16,20]
  float* out = (float*)d_out;               // fp32 [256,96,16]
  char* ws = (char*)d_ws;
  u16*  WtT = (u16*)(ws);                   // 11,796,480 B
  u16*  Xk  = (u16*)(ws + 11796480);        //  1,966,080 B
  u16*  xT  = (u16*)(ws + 13762560);        //  1,966,080 B
  u16*  vT  = (u16*)(ws + 15728640);        //    786,432 B
  u16*  Pb  = (u16*)(ws + 16515072);        // 20 z x 786,432 B = 15,728,640 B
  float* bij = (float*)(ws + 32243712);     //     73,728 B (c-major [c][r])

  k_prep<<<6018, 256, 0, stream>>>(W, X, WtT, Xk, xT, bij);

  for (int it = 0; it < 3; ++it) {
    // s partials: M=256,N=1536,K=3840, grid (2,12,20), 6 k-iters.
    // iter 0: no scale in gemm1; uniform softmax 1/192 applied in redsq.
    gemm1<<<dim3(2, 12, ZSPLIT), 256, 0, stream>>>(Xk, WtT, bij, Pb, it > 0);
    k_redsq<<<dim3(96, 4), 256, 0, stream>>>(
        Pb, out, vT, it == 0 ? (1.0f / 192.0f) : 1.0f, it == 2);
    if (it < 2)
      gemm2_agree<<<dim3(30, 12), 256, 0, stream>>>(xT, vT, WtT, bij);
  }
}

// Round 12
// 158.055 us; speedup vs baseline: 1.1551x; 1.0418x over previous
//
#include <hip/hip_runtime.h>

// DigitCaps dynamic routing, B=256 R=192 C=96 O=16 I=20. fp32 in/out.
// u_hat never materialized. 9 dispatches (DAG floor):
//   prep: W->WtT bf16 k-major; X->Xk + xT; bij=0 (bij C-MAJOR [c][r])
//   gemm1 (x3): 128m x 64n tile, grid (2,24,20)=960 blocks (3.75/CU);
//     A async global_load_lds(16B); B: it0 fully async, else reg-prefetch +
//     wave-local softmax scale at LDS-write; double LDS, 1 barrier/iter;
//     partials transposed bf16 P^T[z][n][b]
//   redsq (x3): grid (96,4); split-K reduce (+preScale) + squash -> vT/out
//   gemm2_agree (x2): 128x64 tile, grid (30,24)=720 blocks, fully async
//     staging; agreement in epilogue vs WtT, atomicAdd bij[c][r]

#define R_ 192
#define C_ 96
#define O_ 16
#define I_ 20
#define B_ 256
#define K1 3840   // R*I
#define N_ 1536   // C*O
#define ZSPLIT 20
#define STILE 393216  // N_*B_ elements per z-slice

typedef unsigned short u16;
typedef __attribute__((ext_vector_type(8))) short short8;
typedef __attribute__((ext_vector_type(4))) float floatx4;

__device__ inline float bf2f(u16 h) {
  union { unsigned int u; float f; } x; x.u = ((unsigned int)h) << 16; return x.f;
}
__device__ inline u16 f2bf(float f) {
  union { float f; unsigned int u; } x; x.f = f;
  unsigned int r = x.u + 0x7FFFu + ((x.u >> 16) & 1u);
  return (u16)(r >> 16);
}
__device__ inline unsigned int pack2(float a, float b) {
  return (unsigned int)f2bf(a) | ((unsigned int)f2bf(b) << 16);
}
// async 16B/lane global->LDS; lds base wave-uniform (lane scatters +16B)
__device__ inline void async16(const u16* g, u16* l) {
  __builtin_amdgcn_global_load_lds(
      (__attribute__((address_space(1))) void*)(unsigned long long)g,
      (__attribute__((address_space(3))) void*)(unsigned int)(unsigned long long)l,
      16, 0, 0);
}

// ---- fused prep: WtT gather (5760 blocks, 4 elems/thr); X cast+transpose
// (240); bij=0 c-major (18)
__global__ void k_prep(const float* __restrict__ W, const float* __restrict__ X,
                       u16* __restrict__ WtT, u16* __restrict__ Xk,
                       u16* __restrict__ xT, float* __restrict__ bij) {
  int bid = blockIdx.x;
  if (bid < 5760) {
    int t = (bid * 256 + threadIdx.x) << 2;    // 4-group stays in one n
    int n = t / K1, k = t - n * K1;
    int c = n >> 4, o = n & 15;
    const float* Wn = W + (size_t)(c * O_ + o) * I_;
    u16 h[4];
    #pragma unroll
    for (int e = 0; e < 4; ++e) {
      int ke = k + e, r = ke / I_, i = ke - r * I_;
      h[e] = f2bf(Wn[(size_t)r * (C_ * O_ * I_) + i]);
    }
    ushort4 o4; o4.x = h[0]; o4.y = h[1]; o4.z = h[2]; o4.w = h[3];
    *(ushort4*)&WtT[t] = o4;
  } else if (bid < 6000) {
    __shared__ u16 tile[64][72];
    int idx = bid - 5760;
    int kb = (idx % 60) << 6, bb = (idx / 60) << 6;
    int brow = threadIdx.x >> 4;          // 0..15
    int kq = (threadIdx.x & 15) << 2;     // 0..60 step 4
    #pragma unroll
    for (int p = 0; p < 4; ++p) {
      int bl = p * 16 + brow;
      float4 v = *(const float4*)(X + (size_t)(bb + bl) * K1 + kb + kq);
      ushort4 h;
      h.x = f2bf(v.x); h.y = f2bf(v.y); h.z = f2bf(v.z); h.w = f2bf(v.w);
      *(ushort4*)(Xk + (size_t)(bb + bl) * K1 + kb + kq) = h;
      tile[kq + 0][bl] = h.x;
      tile[kq + 1][bl] = h.y;
      tile[kq + 2][bl] = h.z;
      tile[kq + 3][bl] = h.w;
    }
    __syncthreads();
    int kr = threadIdx.x >> 3;            // 0..31
    int bq = (threadIdx.x & 7) << 3;      // 0..56 step 8
    #pragma unroll
    for (int q = 0; q < 2; ++q) {
      int kl = q * 32 + kr;
      *(uint4*)(xT + (size_t)(kb + kl) * B_ + bb + bq) = *(const uint4*)&tile[kl][bq];
    }
  } else {
    int t = ((bid - 6000) * 256 + threadIdx.x) << 2;  // bij: 18,432 floats
    if (t < R_ * C_) *(float4*)&bij[t] = (float4){0.f, 0.f, 0.f, 0.f};
  }
}

// scale 8 k-contiguous bf16 (global k = kg..kg+7) by softmax row(s)
__device__ inline uint4 scale_b8(uint4 raw, int kg, const float* smrow) {
  int r0 = kg / I_;
  int bnd = (r0 + 1) * I_ - kg;                // elements j<bnd use r0
  float s0 = smrow[r0];
  float s1 = smrow[(r0 + 1 < R_) ? r0 + 1 : R_ - 1];
  union { uint4 q; u16 h[8]; } u; u.q = raw;
  #pragma unroll
  for (int j = 0; j < 8; ++j)
    u.h[j] = f2bf(bf2f(u.h[j]) * ((j < bnd) ? s0 : s1));
  return u.q;
}

// ---- GEMM1: P^T[z][n][b] bf16 = (Xk[256,3840] x (c*WtT)[1536,3840]^T),
// k-chunk z. 128m x 64n tile, BK=32, 4 waves of 64x32, grid (2,24,20)=960.
// A async; B: doScale -> reg prefetch + wave-local softmax scale at LDS
// write; it0 -> fully async. Double LDS, 1 barrier/iter.
__global__ __launch_bounds__(256) void gemm1(
    const u16* __restrict__ A, const u16* __restrict__ Bt,
    const float* __restrict__ bij, u16* __restrict__ P, int doScale) {
  __shared__ u16 As[2][128 * 32];
  __shared__ u16 Bs[2][64 * 32];
  __shared__ float sm[4][192];
  int tid = threadIdx.x;
  int w = tid >> 6, lane = tid & 63;
  if (doScale) {  // wave-local softmax: wave w owns capsule (by<<2)+w
    int c = (blockIdx.y << 2) + w;
    float e0 = bij[c * R_ + lane];
    float e1 = bij[c * R_ + lane + 64];
    float e2 = bij[c * R_ + lane + 128];
    float mx = fmaxf(e0, fmaxf(e1, e2));
    #pragma unroll
    for (int off = 32; off > 0; off >>= 1) mx = fmaxf(mx, __shfl_xor(mx, off));
    e0 = expf(e0 - mx); e1 = expf(e1 - mx); e2 = expf(e2 - mx);
    float s = e0 + e1 + e2;
    #pragma unroll
    for (int off = 32; off > 0; off >>= 1) s += __shfl_xor(s, off);
    float inv = 1.0f / s;
    sm[w][lane] = e0 * inv;
    sm[w][lane + 64] = e1 * inv;
    sm[w][lane + 128] = e2 * inv;
  }

  long m0 = (long)blockIdx.x * 128, n0 = (long)blockIdx.y * 64;
  int k0 = blockIdx.z * 192;
  const u16* Ab = A + m0 * K1 + k0;
  const u16* Bb = Bt + n0 * K1 + k0;
  int srow = tid >> 2;              // 0..63 (+64 for A's second half)
  int scol = (tid & 3) << 3;        // 0,8,16,24
  int wm = (w >> 1) << 6, wn = (w & 1) << 5;
  int quad = lane >> 4, lrow = lane & 15;
  int wb = w << 9;                  // wave-uniform LDS base (u16 elems)
  const u16* Ag0 = Ab + (long)srow * K1 + scol;
  const u16* Ag1 = Ab + (long)(srow + 64) * K1 + scol;
  const u16* Bg0 = Bb + (long)srow * K1 + scol;
  floatx4 acc[4][2];
  #pragma unroll
  for (int a = 0; a < 4; ++a)
    #pragma unroll
    for (int b = 0; b < 2; ++b) acc[a][b] = (floatx4){0.f, 0.f, 0.f, 0.f};

  // kt=0 staging
  async16(Ag0, &As[0][wb]);
  async16(Ag1, &As[0][2048 + wb]);
  uint4 b0;
  if (doScale) b0 = *(const uint4*)Bg0;
  else         async16(Bg0, &Bs[0][wb]);
  __syncthreads();                   // asyncs drained; sm visible

  int p = 0;
  for (int kt = 0; kt < 6; ++kt) {
    if (doScale) {
      int kg = k0 + (kt << 5) + scol;
      ((uint4*)Bs[p])[tid] = scale_b8(b0, kg, &sm[w][0]);  // row srow's capsule == w
      __syncthreads();               // Bs[p] visible; As[p] async complete
    } else if (kt > 0) {
      __syncthreads();               // buf p asyncs complete
    }
    if (kt + 1 < 6) {                // prefetch escapes the barrier drain
      int kk = (kt + 1) << 5;
      async16(Ag0 + kk, &As[p ^ 1][wb]);
      async16(Ag1 + kk, &As[p ^ 1][2048 + wb]);
      if (doScale) b0 = *(const uint4*)(Bg0 + kk);
      else         async16(Bg0 + kk, &Bs[p ^ 1][wb]);
    }
    short8 af[4], bfr[2];
    #pragma unroll
    for (int ms = 0; ms < 4; ++ms)
      af[ms] = *(const short8*)&As[p][(wm + ms * 16 + lrow) * 32 + (quad << 3)];
    #pragma unroll
    for (int ns = 0; ns < 2; ++ns)
      bfr[ns] = *(const short8*)&Bs[p][(wn + ns * 16 + lrow) * 32 + (quad << 3)];
    #pragma unroll
    for (int ms = 0; ms < 4; ++ms)
      #pragma unroll
      for (int ns = 0; ns < 2; ++ns)
        acc[ms][ns] = __builtin_amdgcn_mfma_f32_16x16x32_bf16(
            af[ms], bfr[ns], acc[ms][ns], 0, 0, 0);
    p ^= 1;
  }
  // transposed bf16 store: P[z][n*256 + b]; lane holds 4 consecutive b
  size_t zb = (size_t)blockIdx.z * (size_t)STILE;
  #pragma unroll
  for (int ms = 0; ms < 4; ++ms)
    #pragma unroll
    for (int ns = 0; ns < 2; ++ns) {
      int b = (int)m0 + wm + ms * 16 + (quad << 2);
      int n = (int)n0 + wn + ns * 16 + lrow;
      uint2 pk;
      pk.x = pack2(acc[ms][ns][0], acc[ms][ns][1]);
      pk.y = pack2(acc[ms][ns][2], acc[ms][ns][3]);
      *(uint2*)&P[zb + (size_t)n * B_ + b] = pk;
    }
}

// ---- fused split-K reduce + squash, reading P^T[z][n][b] bf16.
// grid (96 c, 4 b-quarters); block 256 = 4 o-groups x 64 lanes; 1 b/lane.
__global__ void k_redsq(const u16* __restrict__ P, float* __restrict__ out,
                        u16* __restrict__ vT, float preScale, int last) {
  __shared__ float nsq_l[4][64];
  int c = blockIdx.x, bh = blockIdx.y;
  int lane = threadIdx.x & 63, og = threadIdx.x >> 6;
  int b = (bh << 6) + lane;
  int n0 = (c << 4) + (og << 2);
  float acc[4];
  #pragma unroll
  for (int oo = 0; oo < 4; ++oo) acc[oo] = 0.f;
  #pragma unroll
  for (int z = 0; z < ZSPLIT; ++z) {
    size_t base = (size_t)z * STILE + (size_t)n0 * B_ + b;
    #pragma unroll
    for (int oo = 0; oo < 4; ++oo)
      acc[oo] += bf2f(P[base + (size_t)oo * B_]);
  }
  #pragma unroll
  for (int oo = 0; oo < 4; ++oo) acc[oo] *= preScale;
  float q = acc[0] * acc[0] + acc[1] * acc[1] + acc[2] * acc[2] + acc[3] * acc[3];
  nsq_l[og][lane] = q;
  __syncthreads();
  float nsq = nsq_l[0][lane] + nsq_l[1][lane] + nsq_l[2][lane] + nsq_l[3][lane];
  float f = nsq / ((1.0f + nsq) * sqrtf(nsq));
  #pragma unroll
  for (int oo = 0; oo < 4; ++oo) acc[oo] *= f;
  if (last) {
    *(float4*)(out + (size_t)b * N_ + n0) = (float4){acc[0], acc[1], acc[2], acc[3]};
  } else {
    #pragma unroll
    for (int oo = 0; oo < 4; ++oo)
      vT[(size_t)(n0 + oo) * B_ + b] = f2bf(acc[oo]);
  }
}

// ---- GEMM2 + agreement fused, 128m x 64n tile, grid (30,24), K=256,
// fully async staging; epilogue executed once per tile.
__global__ __launch_bounds__(256) void gemm2_agree(
    const u16* __restrict__ A, const u16* __restrict__ Bt,
    const u16* __restrict__ WtT, float* __restrict__ bij) {
  const int K = 256;
  __shared__ u16 As[2][128 * 32];
  __shared__ u16 Bs[2][64 * 32];
  int tid = threadIdx.x;
  long m0 = (long)blockIdx.x * 128, n0 = (long)blockIdx.y * 64;
  const u16* Ab = A + m0 * K;
  const u16* Bb = Bt + n0 * K;
  int srow = tid >> 2;
  int scol = (tid & 3) << 3;
  int w = tid >> 6, lane = tid & 63;
  int wm = (w >> 1) << 6, wn = (w & 1) << 5;
  int quad = lane >> 4, lrow = lane & 15;
  int wb = w << 9;                  // wave-uniform LDS base (u16 elems)
  const u16* Ag0 = Ab + (long)srow * K + scol;
  const u16* Ag1 = Ab + (long)(srow + 64) * K + scol;
  const u16* Bg0 = Bb + (long)srow * K + scol;
  floatx4 acc[4][2];
  #pragma unroll
  for (int a = 0; a < 4; ++a)
    #pragma unroll
    for (int b = 0; b < 2; ++b) acc[a][b] = (floatx4){0.f, 0.f, 0.f, 0.f};

  async16(Ag0, &As[0][wb]);
  async16(Ag1, &As[0][2048 + wb]);
  async16(Bg0, &Bs[0][wb]);

  int p = 0;
  #pragma unroll
  for (int kt = 0; kt < 8; ++kt) {
    __syncthreads();                 // buf p asyncs complete
    if (kt + 1 < 8) {                // async prefetch escapes the drain
      int kk = (kt + 1) << 5;
      async16(Ag0 + kk, &As[p ^ 1][wb]);
      async16(Ag1 + kk, &As[p ^ 1][2048 + wb]);
      async16(Bg0 + kk, &Bs[p ^ 1][wb]);
    }
    short8 af[4], bfr[2];
    #pragma unroll
    for (int ms = 0; ms < 4; ++ms)
      af[ms] = *(const short8*)&As[p][(wm + ms * 16 + lrow) * 32 + (quad << 3)];
    #pragma unroll
    for (int ns = 0; ns < 2; ++ns)
      bfr[ns] = *(const short8*)&Bs[p][(wn + ns * 16 + lrow) * 32 + (quad << 3)];
    #pragma unroll
    for (int ms = 0; ms < 4; ++ms)
      #pragma unroll
      for (int ns = 0; ns < 2; ++ns)
        acc[ms][ns] = __builtin_amdgcn_mfma_f32_16x16x32_bf16(
            af[ms], bfr[ns], acc[ms][ns], 0, 0, 0);
    p ^= 1;
  }
  // epilogue: per fragment, cols = one capsule c; 16 rows span <=2 routes r.
  #pragma unroll
  for (int ms = 0; ms < 4; ++ms) {
    int rowbase = (int)m0 + wm + ms * 16;          // wave-uniform
    int r_lo = rowbase / I_;
    int r_hi = (rowbase + 15) / I_;
    int bnd = (r_lo + 1) * I_;
    int rowl = rowbase + (quad << 2);
    #pragma unroll
    for (int ns = 0; ns < 2; ++ns) {
      int col = (int)n0 + wn + ns * 16 + lrow;
      uint2 wv = *(const uint2*)&WtT[(size_t)col * K1 + rowl];
      u16 h[4];
      h[0] = (u16)(wv.x & 0xffff); h[1] = (u16)(wv.x >> 16);
      h[2] = (u16)(wv.y & 0xffff); h[3] = (u16)(wv.y >> 16);
      float p0 = 0.f, p1 = 0.f;
      #pragma unroll
      for (int e = 0; e < 4; ++e) {
        float pr = acc[ms][ns][e] * bf2f(h[e]);
        if (rowl + e < bnd) p0 += pr; else p1 += pr;
      }
      #pragma unroll
      for (int off = 32; off > 0; off >>= 1) {
        p0 += __shfl_xor(p0, off);
        p1 += __shfl_xor(p1, off);
      }
      if (lane == 0) {
        int c = col >> 4;
        atomicAdd(&bij[c * R_ + r_lo], p0 * (1.0f / 256.0f));
        atomicAdd(&bij[c * R_ + r_hi], p1 * (1.0f / 256.0f));
      }
    }
  }
}

extern "C" void kernel_launch(void* const* d_in, const int* in_sizes, int n_in,
                              void* d_out, int out_size, void* d_ws, size_t ws_size,
                              hipStream_t stream) {
  const float* X = (const float*)d_in[0];   // fp32 [256,192,20]
  const float* W = (const float*)d_in[1];   // fp32 [192,96,16,20]
  float* out = (float*)d_out;               // fp32 [256,96,16]
  char* ws = (char*)d_ws;
  u16*  WtT = (u16*)(ws);                   // 11,796,480 B
  u16*  Xk  = (u16*)(ws + 11796480);        //  1,966,080 B
  u16*  xT  = (u16*)(ws + 13762560);        //  1,966,080 B
  u16*  vT  = (u16*)(ws + 15728640);        //    786,432 B
  u16*  Pb  = (u16*)(ws + 16515072);        // 20 z x 786,432 B = 15,728,640 B
  float* bij = (float*)(ws + 32243712);     //     73,728 B (c-major [c][r])

  k_prep<<<6018, 256, 0, stream>>>(W, X, WtT, Xk, xT, bij);

  for (int it = 0; it < 3; ++it) {
    // s partials: M=256,N=1536,K=3840, grid (2,24,20)=960, 6 k-iters.
    // iter 0: no scale in gemm1; uniform softmax 1/192 applied in redsq.
    gemm1<<<dim3(2, 24, ZSPLIT), 256, 0, stream>>>(Xk, WtT, bij, Pb, it > 0);
    k_redsq<<<dim3(96, 4), 256, 0, stream>>>(
        Pb, out, vT, it == 0 ? (1.0f / 192.0f) : 1.0f, it == 2);
    if (it < 2)
      gemm2_agree<<<dim3(30, 24), 256, 0, stream>>>(xT, vT, WtT, bij);
  }
}

// Round 13
// 153.254 us; speedup vs baseline: 1.1913x; 1.0313x over previous
//
#include <hip/hip_runtime.h>

// DigitCaps dynamic routing, B=256 R=192 C=96 O=16 I=20. fp32 in/out.
// u_hat never materialized. 9 dispatches (DAG floor):
//   prep: W->WtT bf16 k-major; X->Xk + xT; bij=0 (bij C-MAJOR [c][r])
//   gemm1 (x3): 128m x 64n tile, split-K=15 (kChunk 256, 8 k-iters),
//     grid (2,24,15)=720 blocks; A async global_load_lds(16B); B: it0 fully
//     async, else reg-prefetch + wave-local softmax scale at LDS-write;
//     double LDS, 1 barrier/iter; partials transposed bf16 P^T[z][n][b]
//   redsq (x3): grid (96,4); split-K reduce (+preScale) + squash -> vT/out
//   gemm2_agree (x2): 128x64 tile, grid (30,24)=720 blocks, fully async
//     staging; agreement in epilogue vs WtT, atomicAdd bij[c][r]

#define R_ 192
#define C_ 96
#define O_ 16
#define I_ 20
#define B_ 256
#define K1 3840   // R*I
#define N_ 1536   // C*O
#define ZSPLIT 15
#define KCH 256       // K1/ZSPLIT; 8 BK-iters
#define STILE 393216  // N_*B_ elements per z-slice

typedef unsigned short u16;
typedef __attribute__((ext_vector_type(8))) short short8;
typedef __attribute__((ext_vector_type(4))) float floatx4;

__device__ inline float bf2f(u16 h) {
  union { unsigned int u; float f; } x; x.u = ((unsigned int)h) << 16; return x.f;
}
__device__ inline u16 f2bf(float f) {
  union { float f; unsigned int u; } x; x.f = f;
  unsigned int r = x.u + 0x7FFFu + ((x.u >> 16) & 1u);
  return (u16)(r >> 16);
}
__device__ inline unsigned int pack2(float a, float b) {
  return (unsigned int)f2bf(a) | ((unsigned int)f2bf(b) << 16);
}
// async 16B/lane global->LDS; lds base wave-uniform (lane scatters +16B)
__device__ inline void async16(const u16* g, u16* l) {
  __builtin_amdgcn_global_load_lds(
      (__attribute__((address_space(1))) void*)(unsigned long long)g,
      (__attribute__((address_space(3))) void*)(unsigned int)(unsigned long long)l,
      16, 0, 0);
}

// ---- fused prep: WtT gather (5760 blocks, 4 elems/thr); X cast+transpose
// (240); bij=0 c-major (18)
__global__ void k_prep(const float* __restrict__ W, const float* __restrict__ X,
                       u16* __restrict__ WtT, u16* __restrict__ Xk,
                       u16* __restrict__ xT, float* __restrict__ bij) {
  int bid = blockIdx.x;
  if (bid < 5760) {
    int t = (bid * 256 + threadIdx.x) << 2;    // 4-group stays in one n
    int n = t / K1, k = t - n * K1;
    int c = n >> 4, o = n & 15;
    const float* Wn = W + (size_t)(c * O_ + o) * I_;
    u16 h[4];
    #pragma unroll
    for (int e = 0; e < 4; ++e) {
      int ke = k + e, r = ke / I_, i = ke - r * I_;
      h[e] = f2bf(Wn[(size_t)r * (C_ * O_ * I_) + i]);
    }
    ushort4 o4; o4.x = h[0]; o4.y = h[1]; o4.z = h[2]; o4.w = h[3];
    *(ushort4*)&WtT[t] = o4;
  } else if (bid < 6000) {
    __shared__ u16 tile[64][72];
    int idx = bid - 5760;
    int kb = (idx % 60) << 6, bb = (idx / 60) << 6;
    int brow = threadIdx.x >> 4;          // 0..15
    int kq = (threadIdx.x & 15) << 2;     // 0..60 step 4
    #pragma unroll
    for (int p = 0; p < 4; ++p) {
      int bl = p * 16 + brow;
      float4 v = *(const float4*)(X + (size_t)(bb + bl) * K1 + kb + kq);
      ushort4 h;
      h.x = f2bf(v.x); h.y = f2bf(v.y); h.z = f2bf(v.z); h.w = f2bf(v.w);
      *(ushort4*)(Xk + (size_t)(bb + bl) * K1 + kb + kq) = h;
      tile[kq + 0][bl] = h.x;
      tile[kq + 1][bl] = h.y;
      tile[kq + 2][bl] = h.z;
      tile[kq + 3][bl] = h.w;
    }
    __syncthreads();
    int kr = threadIdx.x >> 3;            // 0..31
    int bq = (threadIdx.x & 7) << 3;      // 0..56 step 8
    #pragma unroll
    for (int q = 0; q < 2; ++q) {
      int kl = q * 32 + kr;
      *(uint4*)(xT + (size_t)(kb + kl) * B_ + bb + bq) = *(const uint4*)&tile[kl][bq];
    }
  } else {
    int t = ((bid - 6000) * 256 + threadIdx.x) << 2;  // bij: 18,432 floats
    if (t < R_ * C_) *(float4*)&bij[t] = (float4){0.f, 0.f, 0.f, 0.f};
  }
}

// scale 8 k-contiguous bf16 (global k = kg..kg+7) by softmax row(s)
__device__ inline uint4 scale_b8(uint4 raw, int kg, const float* smrow) {
  int r0 = kg / I_;
  int bnd = (r0 + 1) * I_ - kg;                // elements j<bnd use r0
  float s0 = smrow[r0];
  float s1 = smrow[(r0 + 1 < R_) ? r0 + 1 : R_ - 1];
  union { uint4 q; u16 h[8]; } u; u.q = raw;
  #pragma unroll
  for (int j = 0; j < 8; ++j)
    u.h[j] = f2bf(bf2f(u.h[j]) * ((j < bnd) ? s0 : s1));
  return u.q;
}

// ---- GEMM1: P^T[z][n][b] bf16 = (Xk[256,3840] x (c*WtT)[1536,3840]^T),
// k-chunk z (256 wide, 8 BK-iters). 128m x 64n tile, 4 waves of 64x32,
// grid (2,24,15)=720. A async; B: doScale -> reg prefetch + wave-local
// softmax scale at LDS write; it0 -> fully async. Double LDS, 1 barrier/iter.
__global__ __launch_bounds__(256) void gemm1(
    const u16* __restrict__ A, const u16* __restrict__ Bt,
    const float* __restrict__ bij, u16* __restrict__ P, int doScale) {
  __shared__ u16 As[2][128 * 32];
  __shared__ u16 Bs[2][64 * 32];
  __shared__ float sm[4][192];
  int tid = threadIdx.x;
  int w = tid >> 6, lane = tid & 63;
  if (doScale) {  // wave-local softmax: wave w owns capsule (by<<2)+w
    int c = (blockIdx.y << 2) + w;
    float e0 = bij[c * R_ + lane];
    float e1 = bij[c * R_ + lane + 64];
    float e2 = bij[c * R_ + lane + 128];
    float mx = fmaxf(e0, fmaxf(e1, e2));
    #pragma unroll
    for (int off = 32; off > 0; off >>= 1) mx = fmaxf(mx, __shfl_xor(mx, off));
    e0 = expf(e0 - mx); e1 = expf(e1 - mx); e2 = expf(e2 - mx);
    float s = e0 + e1 + e2;
    #pragma unroll
    for (int off = 32; off > 0; off >>= 1) s += __shfl_xor(s, off);
    float inv = 1.0f / s;
    sm[w][lane] = e0 * inv;
    sm[w][lane + 64] = e1 * inv;
    sm[w][lane + 128] = e2 * inv;
  }

  long m0 = (long)blockIdx.x * 128, n0 = (long)blockIdx.y * 64;
  int k0 = blockIdx.z * KCH;
  const u16* Ab = A + m0 * K1 + k0;
  const u16* Bb = Bt + n0 * K1 + k0;
  int srow = tid >> 2;              // 0..63 (+64 for A's second half)
  int scol = (tid & 3) << 3;        // 0,8,16,24
  int wm = (w >> 1) << 6, wn = (w & 1) << 5;
  int quad = lane >> 4, lrow = lane & 15;
  int wb = w << 9;                  // wave-uniform LDS base (u16 elems)
  const u16* Ag0 = Ab + (long)srow * K1 + scol;
  const u16* Ag1 = Ab + (long)(srow + 64) * K1 + scol;
  const u16* Bg0 = Bb + (long)srow * K1 + scol;
  floatx4 acc[4][2];
  #pragma unroll
  for (int a = 0; a < 4; ++a)
    #pragma unroll
    for (int b = 0; b < 2; ++b) acc[a][b] = (floatx4){0.f, 0.f, 0.f, 0.f};

  // kt=0 staging
  async16(Ag0, &As[0][wb]);
  async16(Ag1, &As[0][2048 + wb]);
  uint4 b0;
  if (doScale) b0 = *(const uint4*)Bg0;
  else         async16(Bg0, &Bs[0][wb]);
  __syncthreads();                   // asyncs drained; sm visible

  int p = 0;
  for (int kt = 0; kt < 8; ++kt) {
    if (doScale) {
      int kg = k0 + (kt << 5) + scol;
      ((uint4*)Bs[p])[tid] = scale_b8(b0, kg, &sm[w][0]);  // row srow's capsule == w
      __syncthreads();               // Bs[p] visible; As[p] async complete
    } else if (kt > 0) {
      __syncthreads();               // buf p asyncs complete
    }
    if (kt + 1 < 8) {                // prefetch escapes the barrier drain
      int kk = (kt + 1) << 5;
      async16(Ag0 + kk, &As[p ^ 1][wb]);
      async16(Ag1 + kk, &As[p ^ 1][2048 + wb]);
      if (doScale) b0 = *(const uint4*)(Bg0 + kk);
      else         async16(Bg0 + kk, &Bs[p ^ 1][wb]);
    }
    short8 af[4], bfr[2];
    #pragma unroll
    for (int ms = 0; ms < 4; ++ms)
      af[ms] = *(const short8*)&As[p][(wm + ms * 16 + lrow) * 32 + (quad << 3)];
    #pragma unroll
    for (int ns = 0; ns < 2; ++ns)
      bfr[ns] = *(const short8*)&Bs[p][(wn + ns * 16 + lrow) * 32 + (quad << 3)];
    #pragma unroll
    for (int ms = 0; ms < 4; ++ms)
      #pragma unroll
      for (int ns = 0; ns < 2; ++ns)
        acc[ms][ns] = __builtin_amdgcn_mfma_f32_16x16x32_bf16(
            af[ms], bfr[ns], acc[ms][ns], 0, 0, 0);
    p ^= 1;
  }
  // transposed bf16 store: P[z][n*256 + b]; lane holds 4 consecutive b
  size_t zb = (size_t)blockIdx.z * (size_t)STILE;
  #pragma unroll
  for (int ms = 0; ms < 4; ++ms)
    #pragma unroll
    for (int ns = 0; ns < 2; ++ns) {
      int b = (int)m0 + wm + ms * 16 + (quad << 2);
      int n = (int)n0 + wn + ns * 16 + lrow;
      uint2 pk;
      pk.x = pack2(acc[ms][ns][0], acc[ms][ns][1]);
      pk.y = pack2(acc[ms][ns][2], acc[ms][ns][3]);
      *(uint2*)&P[zb + (size_t)n * B_ + b] = pk;
    }
}

// ---- fused split-K reduce + squash, reading P^T[z][n][b] bf16.
// grid (96 c, 4 b-quarters); block 256 = 4 o-groups x 64 lanes; 1 b/lane.
__global__ void k_redsq(const u16* __restrict__ P, float* __restrict__ out,
                        u16* __restrict__ vT, float preScale, int last) {
  __shared__ float nsq_l[4][64];
  int c = blockIdx.x, bh = blockIdx.y;
  int lane = threadIdx.x & 63, og = threadIdx.x >> 6;
  int b = (bh << 6) + lane;
  int n0 = (c << 4) + (og << 2);
  float acc[4];
  #pragma unroll
  for (int oo = 0; oo < 4; ++oo) acc[oo] = 0.f;
  #pragma unroll
  for (int z = 0; z < ZSPLIT; ++z) {
    size_t base = (size_t)z * STILE + (size_t)n0 * B_ + b;
    #pragma unroll
    for (int oo = 0; oo < 4; ++oo)
      acc[oo] += bf2f(P[base + (size_t)oo * B_]);
  }
  #pragma unroll
  for (int oo = 0; oo < 4; ++oo) acc[oo] *= preScale;
  float q = acc[0] * acc[0] + acc[1] * acc[1] + acc[2] * acc[2] + acc[3] * acc[3];
  nsq_l[og][lane] = q;
  __syncthreads();
  float nsq = nsq_l[0][lane] + nsq_l[1][lane] + nsq_l[2][lane] + nsq_l[3][lane];
  float f = nsq / ((1.0f + nsq) * sqrtf(nsq));
  #pragma unroll
  for (int oo = 0; oo < 4; ++oo) acc[oo] *= f;
  if (last) {
    *(float4*)(out + (size_t)b * N_ + n0) = (float4){acc[0], acc[1], acc[2], acc[3]};
  } else {
    #pragma unroll
    for (int oo = 0; oo < 4; ++oo)
      vT[(size_t)(n0 + oo) * B_ + b] = f2bf(acc[oo]);
  }
}

// ---- GEMM2 + agreement fused, 128m x 64n tile, grid (30,24), K=256,
// fully async staging; epilogue executed once per tile.
__global__ __launch_bounds__(256) void gemm2_agree(
    const u16* __restrict__ A, const u16* __restrict__ Bt,
    const u16* __restrict__ WtT, float* __restrict__ bij) {
  const int K = 256;
  __shared__ u16 As[2][128 * 32];
  __shared__ u16 Bs[2][64 * 32];
  int tid = threadIdx.x;
  long m0 = (long)blockIdx.x * 128, n0 = (long)blockIdx.y * 64;
  const u16* Ab = A + m0 * K;
  const u16* Bb = Bt + n0 * K;
  int srow = tid >> 2;
  int scol = (tid & 3) << 3;
  int w = tid >> 6, lane = tid & 63;
  int wm = (w >> 1) << 6, wn = (w & 1) << 5;
  int quad = lane >> 4, lrow = lane & 15;
  int wb = w << 9;                  // wave-uniform LDS base (u16 elems)
  const u16* Ag0 = Ab + (long)srow * K + scol;
  const u16* Ag1 = Ab + (long)(srow + 64) * K + scol;
  const u16* Bg0 = Bb + (long)srow * K + scol;
  floatx4 acc[4][2];
  #pragma unroll
  for (int a = 0; a < 4; ++a)
    #pragma unroll
    for (int b = 0; b < 2; ++b) acc[a][b] = (floatx4){0.f, 0.f, 0.f, 0.f};

  async16(Ag0, &As[0][wb]);
  async16(Ag1, &As[0][2048 + wb]);
  async16(Bg0, &Bs[0][wb]);

  int p = 0;
  #pragma unroll
  for (int kt = 0; kt < 8; ++kt) {
    __syncthreads();                 // buf p asyncs complete
    if (kt + 1 < 8) {                // async prefetch escapes the drain
      int kk = (kt + 1) << 5;
      async16(Ag0 + kk, &As[p ^ 1][wb]);
      async16(Ag1 + kk, &As[p ^ 1][2048 + wb]);
      async16(Bg0 + kk, &Bs[p ^ 1][wb]);
    }
    short8 af[4], bfr[2];
    #pragma unroll
    for (int ms = 0; ms < 4; ++ms)
      af[ms] = *(const short8*)&As[p][(wm + ms * 16 + lrow) * 32 + (quad << 3)];
    #pragma unroll
    for (int ns = 0; ns < 2; ++ns)
      bfr[ns] = *(const short8*)&Bs[p][(wn + ns * 16 + lrow) * 32 + (quad << 3)];
    #pragma unroll
    for (int ms = 0; ms < 4; ++ms)
      #pragma unroll
      for (int ns = 0; ns < 2; ++ns)
        acc[ms][ns] = __builtin_amdgcn_mfma_f32_16x16x32_bf16(
            af[ms], bfr[ns], acc[ms][ns], 0, 0, 0);
    p ^= 1;
  }
  // epilogue: per fragment, cols = one capsule c; 16 rows span <=2 routes r.
  #pragma unroll
  for (int ms = 0; ms < 4; ++ms) {
    int rowbase = (int)m0 + wm + ms * 16;          // wave-uniform
    int r_lo = rowbase / I_;
    int r_hi = (rowbase + 15) / I_;
    int bnd = (r_lo + 1) * I_;
    int rowl = rowbase + (quad << 2);
    #pragma unroll
    for (int ns = 0; ns < 2; ++ns) {
      int col = (int)n0 + wn + ns * 16 + lrow;
      uint2 wv = *(const uint2*)&WtT[(size_t)col * K1 + rowl];
      u16 h[4];
      h[0] = (u16)(wv.x & 0xffff); h[1] = (u16)(wv.x >> 16);
      h[2] = (u16)(wv.y & 0xffff); h[3] = (u16)(wv.y >> 16);
      float p0 = 0.f, p1 = 0.f;
      #pragma unroll
      for (int e = 0; e < 4; ++e) {
        float pr = acc[ms][ns][e] * bf2f(h[e]);
        if (rowl + e < bnd) p0 += pr; else p1 += pr;
      }
      #pragma unroll
      for (int off = 32; off > 0; off >>= 1) {
        p0 += __shfl_xor(p0, off);
        p1 += __shfl_xor(p1, off);
      }
      if (lane == 0) {
        int c = col >> 4;
        atomicAdd(&bij[c * R_ + r_lo], p0 * (1.0f / 256.0f));
        atomicAdd(&bij[c * R_ + r_hi], p1 * (1.0f / 256.0f));
      }
    }
  }
}

extern "C" void kernel_launch(void* const* d_in, const int* in_sizes, int n_in,
                              void* d_out, int out_size, void* d_ws, size_t ws_size,
                              hipStream_t stream) {
  const float* X = (const float*)d_in[0];   // fp32 [256,192,20]
  const float* W = (const float*)d_in[1];   // fp32 [192,96,16,20]
  float* out = (float*)d_out;               // fp32 [256,96,16]
  char* ws = (char*)d_ws;
  u16*  WtT = (u16*)(ws);                   // 11,796,480 B
  u16*  Xk  = (u16*)(ws + 11796480);        //  1,966,080 B
  u16*  xT  = (u16*)(ws + 13762560);        //  1,966,080 B
  u16*  vT  = (u16*)(ws + 15728640);        //    786,432 B
  u16*  Pb  = (u16*)(ws + 16515072);        // 15 z x 786,432 B = 11,796,480 B
  float* bij = (float*)(ws + 28311552);     //     73,728 B (c-major [c][r])

  k_prep<<<6018, 256, 0, stream>>>(W, X, WtT, Xk, xT, bij);

  for (int it = 0; it < 3; ++it) {
    // s partials: M=256,N=1536,K=3840, grid (2,24,15)=720, 8 k-iters.
    // iter 0: no scale in gemm1; uniform softmax 1/192 applied in redsq.
    gemm1<<<dim3(2, 24, ZSPLIT), 256, 0, stream>>>(Xk, WtT, bij, Pb, it > 0);
    k_redsq<<<dim3(96, 4), 256, 0, stream>>>(
        Pb, out, vT, it == 0 ? (1.0f / 192.0f) : 1.0f, it == 2);
    if (it < 2)
      gemm2_agree<<<dim3(30, 24), 256, 0, stream>>>(xT, vT, WtT, bij);
  }
}

// Round 14
// 147.849 us; speedup vs baseline: 1.2349x; 1.0366x over previous
//
#include <hip/hip_runtime.h>

// DigitCaps dynamic routing, B=256 R=192 C=96 O=16 I=20. fp32 in/out.
// u_hat never materialized. 9 dispatches (DAG floor):
//   prep: W->WtT bf16 k-major; X->Xk + xT; bij=0 (bij C-MAJOR [c][r])
//   gemm1 (x3): 128m x 64n tile, split-K=15 (kChunk 256 = 4 iters of BK64,
//     each iter = 2 BK32 sub-tiles sharing ONE barrier), grid (2,24,15)=720;
//     A async global_load_lds(16B); B: it0 fully async, else reg-prefetch +
//     wave-local softmax scale at LDS-write; double LDS; partials bf16
//     P^T[z][n][b]
//   redsq (x3): grid (96,4); split-K reduce (+preScale) + squash -> vT/out
//   gemm2_agree (x2): 128x64 tile, grid (30,24), BK64 sub-tile pairs (4
//     barriers), fully async; agreement in epilogue vs WtT, atomicAdd bij

#define R_ 192
#define C_ 96
#define O_ 16
#define I_ 20
#define B_ 256
#define K1 3840   // R*I
#define N_ 1536   // C*O
#define ZSPLIT 15
#define KCH 256       // K1/ZSPLIT; 4 iters of BK=64 (2x BK32 sub-tiles)
#define STILE 393216  // N_*B_ elements per z-slice

typedef unsigned short u16;
typedef __attribute__((ext_vector_type(8))) short short8;
typedef __attribute__((ext_vector_type(4))) float floatx4;

__device__ inline float bf2f(u16 h) {
  union { unsigned int u; float f; } x; x.u = ((unsigned int)h) << 16; return x.f;
}
__device__ inline u16 f2bf(float f) {
  union { float f; unsigned int u; } x; x.f = f;
  unsigned int r = x.u + 0x7FFFu + ((x.u >> 16) & 1u);
  return (u16)(r >> 16);
}
__device__ inline unsigned int pack2(float a, float b) {
  return (unsigned int)f2bf(a) | ((unsigned int)f2bf(b) << 16);
}
// async 16B/lane global->LDS; lds base wave-uniform (lane scatters +16B)
__device__ inline void async16(const u16* g, u16* l) {
  __builtin_amdgcn_global_load_lds(
      (__attribute__((address_space(1))) void*)(unsigned long long)g,
      (__attribute__((address_space(3))) void*)(unsigned int)(unsigned long long)l,
      16, 0, 0);
}

// ---- fused prep: WtT gather (5760 blocks, 4 elems/thr); X cast+transpose
// (240); bij=0 c-major (18)
__global__ void k_prep(const float* __restrict__ W, const float* __restrict__ X,
                       u16* __restrict__ WtT, u16* __restrict__ Xk,
                       u16* __restrict__ xT, float* __restrict__ bij) {
  int bid = blockIdx.x;
  if (bid < 5760) {
    int t = (bid * 256 + threadIdx.x) << 2;    // 4-group stays in one n
    int n = t / K1, k = t - n * K1;
    int c = n >> 4, o = n & 15;
    const float* Wn = W + (size_t)(c * O_ + o) * I_;
    u16 h[4];
    #pragma unroll
    for (int e = 0; e < 4; ++e) {
      int ke = k + e, r = ke / I_, i = ke - r * I_;
      h[e] = f2bf(Wn[(size_t)r * (C_ * O_ * I_) + i]);
    }
    ushort4 o4; o4.x = h[0]; o4.y = h[1]; o4.z = h[2]; o4.w = h[3];
    *(ushort4*)&WtT[t] = o4;
  } else if (bid < 6000) {
    __shared__ u16 tile[64][72];
    int idx = bid - 5760;
    int kb = (idx % 60) << 6, bb = (idx / 60) << 6;
    int brow = threadIdx.x >> 4;          // 0..15
    int kq = (threadIdx.x & 15) << 2;     // 0..60 step 4
    #pragma unroll
    for (int p = 0; p < 4; ++p) {
      int bl = p * 16 + brow;
      float4 v = *(const float4*)(X + (size_t)(bb + bl) * K1 + kb + kq);
      ushort4 h;
      h.x = f2bf(v.x); h.y = f2bf(v.y); h.z = f2bf(v.z); h.w = f2bf(v.w);
      *(ushort4*)(Xk + (size_t)(bb + bl) * K1 + kb + kq) = h;
      tile[kq + 0][bl] = h.x;
      tile[kq + 1][bl] = h.y;
      tile[kq + 2][bl] = h.z;
      tile[kq + 3][bl] = h.w;
    }
    __syncthreads();
    int kr = threadIdx.x >> 3;            // 0..31
    int bq = (threadIdx.x & 7) << 3;      // 0..56 step 8
    #pragma unroll
    for (int q = 0; q < 2; ++q) {
      int kl = q * 32 + kr;
      *(uint4*)(xT + (size_t)(kb + kl) * B_ + bb + bq) = *(const uint4*)&tile[kl][bq];
    }
  } else {
    int t = ((bid - 6000) * 256 + threadIdx.x) << 2;  // bij: 18,432 floats
    if (t < R_ * C_) *(float4*)&bij[t] = (float4){0.f, 0.f, 0.f, 0.f};
  }
}

// scale 8 k-contiguous bf16 (global k = kg..kg+7) by softmax row(s)
__device__ inline uint4 scale_b8(uint4 raw, int kg, const float* smrow) {
  int r0 = kg / I_;
  int bnd = (r0 + 1) * I_ - kg;                // elements j<bnd use r0
  float s0 = smrow[r0];
  float s1 = smrow[(r0 + 1 < R_) ? r0 + 1 : R_ - 1];
  union { uint4 q; u16 h[8]; } u; u.q = raw;
  #pragma unroll
  for (int j = 0; j < 8; ++j)
    u.h[j] = f2bf(bf2f(u.h[j]) * ((j < bnd) ? s0 : s1));
  return u.q;
}

// ---- GEMM1: P^T[z][n][b] bf16 = (Xk[256,3840] x (c*WtT)[1536,3840]^T),
// k-chunk z (256 = 4 x BK64; each BK64 = 2 BK32 sub-tiles, ONE barrier).
// 128m x 64n tile, 4 waves of 64x32, grid (2,24,15)=720.
__global__ __launch_bounds__(256) void gemm1(
    const u16* __restrict__ A, const u16* __restrict__ Bt,
    const float* __restrict__ bij, u16* __restrict__ P, int doScale) {
  __shared__ u16 As[2][2][128 * 32];   // [buf][sub][...] 32 KB
  __shared__ u16 Bs[2][2][64 * 32];    // 16 KB
  __shared__ float sm[4][192];
  int tid = threadIdx.x;
  int w = tid >> 6, lane = tid & 63;
  if (doScale) {  // wave-local softmax: wave w owns capsule (by<<2)+w
    int c = (blockIdx.y << 2) + w;
    float e0 = bij[c * R_ + lane];
    float e1 = bij[c * R_ + lane + 64];
    float e2 = bij[c * R_ + lane + 128];
    float mx = fmaxf(e0, fmaxf(e1, e2));
    #pragma unroll
    for (int off = 32; off > 0; off >>= 1) mx = fmaxf(mx, __shfl_xor(mx, off));
    e0 = expf(e0 - mx); e1 = expf(e1 - mx); e2 = expf(e2 - mx);
    float s = e0 + e1 + e2;
    #pragma unroll
    for (int off = 32; off > 0; off >>= 1) s += __shfl_xor(s, off);
    float inv = 1.0f / s;
    sm[w][lane] = e0 * inv;
    sm[w][lane + 64] = e1 * inv;
    sm[w][lane + 128] = e2 * inv;
  }

  long m0 = (long)blockIdx.x * 128, n0 = (long)blockIdx.y * 64;
  int k0 = blockIdx.z * KCH;
  const u16* Ab = A + m0 * K1 + k0;
  const u16* Bb = Bt + n0 * K1 + k0;
  int srow = tid >> 2;              // 0..63
  int scol = (tid & 3) << 3;        // 0,8,16,24
  int wm = (w >> 1) << 6, wn = (w & 1) << 5;
  int quad = lane >> 4, lrow = lane & 15;
  int wb = w << 9;                  // wave-uniform LDS base (u16 elems)
  const u16* Ag0 = Ab + (long)srow * K1 + scol;
  const u16* Ag1 = Ab + (long)(srow + 64) * K1 + scol;
  const u16* Bg0 = Bb + (long)srow * K1 + scol;
  floatx4 acc[4][2];
  #pragma unroll
  for (int a = 0; a < 4; ++a)
    #pragma unroll
    for (int b = 0; b < 2; ++b) acc[a][b] = (floatx4){0.f, 0.f, 0.f, 0.f};

  // kt=0 staging: both sub-tiles
  async16(Ag0, &As[0][0][wb]);
  async16(Ag1, &As[0][0][2048 + wb]);
  async16(Ag0 + 32, &As[0][1][wb]);
  async16(Ag1 + 32, &As[0][1][2048 + wb]);
  uint4 b0, b1;
  if (doScale) {
    b0 = *(const uint4*)Bg0;
    b1 = *(const uint4*)(Bg0 + 32);
  } else {
    async16(Bg0, &Bs[0][0][wb]);
    async16(Bg0 + 32, &Bs[0][1][wb]);
  }
  __syncthreads();                   // asyncs drained; sm visible

  int p = 0;
  for (int kt = 0; kt < 4; ++kt) {
    if (doScale) {                   // capsule of B row srow == w (tid>>6)
      int kg = k0 + (kt << 6) + scol;
      ((uint4*)Bs[p][0])[tid] = scale_b8(b0, kg, &sm[w][0]);
      ((uint4*)Bs[p][1])[tid] = scale_b8(b1, kg + 32, &sm[w][0]);
      __syncthreads();               // Bs[p] visible; As[p] asyncs complete
    } else if (kt > 0) {
      __syncthreads();               // buf p asyncs complete
    }
    if (kt + 1 < 4) {                // prefetch escapes the barrier drain
      int kk = (kt + 1) << 6;
      async16(Ag0 + kk, &As[p ^ 1][0][wb]);
      async16(Ag1 + kk, &As[p ^ 1][0][2048 + wb]);
      async16(Ag0 + kk + 32, &As[p ^ 1][1][wb]);
      async16(Ag1 + kk + 32, &As[p ^ 1][1][2048 + wb]);
      if (doScale) {
        b0 = *(const uint4*)(Bg0 + kk);
        b1 = *(const uint4*)(Bg0 + kk + 32);
      } else {
        async16(Bg0 + kk, &Bs[p ^ 1][0][wb]);
        async16(Bg0 + kk + 32, &Bs[p ^ 1][1][wb]);
      }
    }
    #pragma unroll
    for (int s = 0; s < 2; ++s) {
      short8 af[4], bfr[2];
      #pragma unroll
      for (int ms = 0; ms < 4; ++ms)
        af[ms] = *(const short8*)&As[p][s][(wm + ms * 16 + lrow) * 32 + (quad << 3)];
      #pragma unroll
      for (int ns = 0; ns < 2; ++ns)
        bfr[ns] = *(const short8*)&Bs[p][s][(wn + ns * 16 + lrow) * 32 + (quad << 3)];
      #pragma unroll
      for (int ms = 0; ms < 4; ++ms)
        #pragma unroll
        for (int ns = 0; ns < 2; ++ns)
          acc[ms][ns] = __builtin_amdgcn_mfma_f32_16x16x32_bf16(
              af[ms], bfr[ns], acc[ms][ns], 0, 0, 0);
    }
    p ^= 1;
  }
  // transposed bf16 store: P[z][n*256 + b]; lane holds 4 consecutive b
  size_t zb = (size_t)blockIdx.z * (size_t)STILE;
  #pragma unroll
  for (int ms = 0; ms < 4; ++ms)
    #pragma unroll
    for (int ns = 0; ns < 2; ++ns) {
      int b = (int)m0 + wm + ms * 16 + (quad << 2);
      int n = (int)n0 + wn + ns * 16 + lrow;
      uint2 pk;
      pk.x = pack2(acc[ms][ns][0], acc[ms][ns][1]);
      pk.y = pack2(acc[ms][ns][2], acc[ms][ns][3]);
      *(uint2*)&P[zb + (size_t)n * B_ + b] = pk;
    }
}

// ---- fused split-K reduce + squash, reading P^T[z][n][b] bf16.
// grid (96 c, 4 b-quarters); block 256 = 4 o-groups x 64 lanes; 1 b/lane.
__global__ void k_redsq(const u16* __restrict__ P, float* __restrict__ out,
                        u16* __restrict__ vT, float preScale, int last) {
  __shared__ float nsq_l[4][64];
  int c = blockIdx.x, bh = blockIdx.y;
  int lane = threadIdx.x & 63, og = threadIdx.x >> 6;
  int b = (bh << 6) + lane;
  int n0 = (c << 4) + (og << 2);
  float acc[4];
  #pragma unroll
  for (int oo = 0; oo < 4; ++oo) acc[oo] = 0.f;
  #pragma unroll
  for (int z = 0; z < ZSPLIT; ++z) {
    size_t base = (size_t)z * STILE + (size_t)n0 * B_ + b;
    #pragma unroll
    for (int oo = 0; oo < 4; ++oo)
      acc[oo] += bf2f(P[base + (size_t)oo * B_]);
  }
  #pragma unroll
  for (int oo = 0; oo < 4; ++oo) acc[oo] *= preScale;
  float q = acc[0] * acc[0] + acc[1] * acc[1] + acc[2] * acc[2] + acc[3] * acc[3];
  nsq_l[og][lane] = q;
  __syncthreads();
  float nsq = nsq_l[0][lane] + nsq_l[1][lane] + nsq_l[2][lane] + nsq_l[3][lane];
  float f = nsq / ((1.0f + nsq) * sqrtf(nsq));
  #pragma unroll
  for (int oo = 0; oo < 4; ++oo) acc[oo] *= f;
  if (last) {
    *(float4*)(out + (size_t)b * N_ + n0) = (float4){acc[0], acc[1], acc[2], acc[3]};
  } else {
    #pragma unroll
    for (int oo = 0; oo < 4; ++oo)
      vT[(size_t)(n0 + oo) * B_ + b] = f2bf(acc[oo]);
  }
}

// ---- GEMM2 + agreement fused, 128m x 64n tile, grid (30,24), K=256 =
// 4 x BK64 (2 BK32 sub-tiles per barrier), fully async staging.
__global__ __launch_bounds__(256) void gemm2_agree(
    const u16* __restrict__ A, const u16* __restrict__ Bt,
    const u16* __restrict__ WtT, float* __restrict__ bij) {
  const int K = 256;
  __shared__ u16 As[2][2][128 * 32];
  __shared__ u16 Bs[2][2][64 * 32];
  int tid = threadIdx.x;
  long m0 = (long)blockIdx.x * 128, n0 = (long)blockIdx.y * 64;
  const u16* Ab = A + m0 * K;
  const u16* Bb = Bt + n0 * K;
  int srow = tid >> 2;
  int scol = (tid & 3) << 3;
  int w = tid >> 6, lane = tid & 63;
  int wm = (w >> 1) << 6, wn = (w & 1) << 5;
  int quad = lane >> 4, lrow = lane & 15;
  int wb = w << 9;                  // wave-uniform LDS base (u16 elems)
  const u16* Ag0 = Ab + (long)srow * K + scol;
  const u16* Ag1 = Ab + (long)(srow + 64) * K + scol;
  const u16* Bg0 = Bb + (long)srow * K + scol;
  floatx4 acc[4][2];
  #pragma unroll
  for (int a = 0; a < 4; ++a)
    #pragma unroll
    for (int b = 0; b < 2; ++b) acc[a][b] = (floatx4){0.f, 0.f, 0.f, 0.f};

  async16(Ag0, &As[0][0][wb]);
  async16(Ag1, &As[0][0][2048 + wb]);
  async16(Ag0 + 32, &As[0][1][wb]);
  async16(Ag1 + 32, &As[0][1][2048 + wb]);
  async16(Bg0, &Bs[0][0][wb]);
  async16(Bg0 + 32, &Bs[0][1][wb]);

  int p = 0;
  #pragma unroll
  for (int kt = 0; kt < 4; ++kt) {
    __syncthreads();                 // buf p asyncs complete
    if (kt + 1 < 4) {                // async prefetch escapes the drain
      int kk = (kt + 1) << 6;
      async16(Ag0 + kk, &As[p ^ 1][0][wb]);
      async16(Ag1 + kk, &As[p ^ 1][0][2048 + wb]);
      async16(Ag0 + kk + 32, &As[p ^ 1][1][wb]);
      async16(Ag1 + kk + 32, &As[p ^ 1][1][2048 + wb]);
      async16(Bg0 + kk, &Bs[p ^ 1][0][wb]);
      async16(Bg0 + kk + 32, &Bs[p ^ 1][1][wb]);
    }
    #pragma unroll
    for (int s = 0; s < 2; ++s) {
      short8 af[4], bfr[2];
      #pragma unroll
      for (int ms = 0; ms < 4; ++ms)
        af[ms] = *(const short8*)&As[p][s][(wm + ms * 16 + lrow) * 32 + (quad << 3)];
      #pragma unroll
      for (int ns = 0; ns < 2; ++ns)
        bfr[ns] = *(const short8*)&Bs[p][s][(wn + ns * 16 + lrow) * 32 + (quad << 3)];
      #pragma unroll
      for (int ms = 0; ms < 4; ++ms)
        #pragma unroll
        for (int ns = 0; ns < 2; ++ns)
          acc[ms][ns] = __builtin_amdgcn_mfma_f32_16x16x32_bf16(
              af[ms], bfr[ns], acc[ms][ns], 0, 0, 0);
    }
    p ^= 1;
  }
  // epilogue: per fragment, cols = one capsule c; 16 rows span <=2 routes r.
  #pragma unroll
  for (int ms = 0; ms < 4; ++ms) {
    int rowbase = (int)m0 + wm + ms * 16;          // wave-uniform
    int r_lo = rowbase / I_;
    int r_hi = (rowbase + 15) / I_;
    int bnd = (r_lo + 1) * I_;
    int rowl = rowbase + (quad << 2);
    #pragma unroll
    for (int ns = 0; ns < 2; ++ns) {
      int col = (int)n0 + wn + ns * 16 + lrow;
      uint2 wv = *(const uint2*)&WtT[(size_t)col * K1 + rowl];
      u16 h[4];
      h[0] = (u16)(wv.x & 0xffff); h[1] = (u16)(wv.x >> 16);
      h[2] = (u16)(wv.y & 0xffff); h[3] = (u16)(wv.y >> 16);
      float p0 = 0.f, p1 = 0.f;
      #pragma unroll
      for (int e = 0; e < 4; ++e) {
        float pr = acc[ms][ns][e] * bf2f(h[e]);
        if (rowl + e < bnd) p0 += pr; else p1 += pr;
      }
      #pragma unroll
      for (int off = 32; off > 0; off >>= 1) {
        p0 += __shfl_xor(p0, off);
        p1 += __shfl_xor(p1, off);
      }
      if (lane == 0) {
        int c = col >> 4;
        atomicAdd(&bij[c * R_ + r_lo], p0 * (1.0f / 256.0f));
        atomicAdd(&bij[c * R_ + r_hi], p1 * (1.0f / 256.0f));
      }
    }
  }
}

extern "C" void kernel_launch(void* const* d_in, const int* in_sizes, int n_in,
                              void* d_out, int out_size, void* d_ws, size_t ws_size,
                              hipStream_t stream) {
  const float* X = (const float*)d_in[0];   // fp32 [256,192,20]
  const float* W = (const float*)d_in[1];   // fp32 [192,96,16,20]
  float* out = (float*)d_out;               // fp32 [256,96,16]
  char* ws = (char*)d_ws;
  u16*  WtT = (u16*)(ws);                   // 11,796,480 B
  u16*  Xk  = (u16*)(ws + 11796480);        //  1,966,080 B
  u16*  xT  = (u16*)(ws + 13762560);        //  1,966,080 B
  u16*  vT  = (u16*)(ws + 15728640);        //    786,432 B
  u16*  Pb  = (u16*)(ws + 16515072);        // 15 z x 786,432 B = 11,796,480 B
  float* bij = (float*)(ws + 28311552);     //     73,728 B (c-major [c][r])

  k_prep<<<6018, 256, 0, stream>>>(W, X, WtT, Xk, xT, bij);

  for (int it = 0; it < 3; ++it) {
    // s partials: M=256,N=1536,K=3840, grid (2,24,15)=720, 4 BK64 iters.
    // iter 0: no scale in gemm1; uniform softmax 1/192 applied in redsq.
    gemm1<<<dim3(2, 24, ZSPLIT), 256, 0, stream>>>(Xk, WtT, bij, Pb, it > 0);
    k_redsq<<<dim3(96, 4), 256, 0, stream>>>(
        Pb, out, vT, it == 0 ? (1.0f / 192.0f) : 1.0f, it == 2);
    if (it < 2)
      gemm2_agree<<<dim3(30, 24), 256, 0, stream>>>(xT, vT, WtT, bij);
  }
}